// Round 1
// baseline (3232.519 us; speedup 1.0000x reference)
//
#include <hip/hip_runtime.h>
#include <hip/hip_bf16.h>
#include <math.h>

// Problem constants (from reference): B=16, N=1024, F=64, T=24, K=3, FO=64
#define Bc 16
#define Nc 1024
#define Fc 64
#define Tc 24
#define Kc 3
#define FOc 64
#define Cc (Fc*Tc)   // 1536 = flattened (f,t)

// ---------------------------------------------------------------------------
// Phase 1: per (b,n): lhs[b,n,t'] = sum_f (sum_t x[b,n,f,t]*W1[t]) * W2[f,t']
//                      rhs[b,n,t]  = sum_f W3[f]*x[b,n,f,t]
// One 64-thread block per (b,n). x row (f,t) staged in LDS (stride 25 pad).
// ---------------------------------------------------------------------------
__global__ __launch_bounds__(64) void prep_kernel(
    const float* __restrict__ x, const float* __restrict__ W1,
    const float* __restrict__ W2, const float* __restrict__ W3,
    float* __restrict__ lhs, float* __restrict__ rhs) {
  int bn = blockIdx.x;
  int tid = threadIdx.x;
  __shared__ float xs[Fc * 25];
  __shared__ float w1s[Tc];
  __shared__ float w3s[Fc];
  __shared__ float af[Fc];
  const float* xp = x + (size_t)bn * Cc;
  for (int i = tid; i < Cc; i += 64) {
    xs[(i / Tc) * 25 + (i % Tc)] = xp[i];
  }
  if (tid < Tc) w1s[tid] = W1[tid];
  w3s[tid] = W3[tid];
  __syncthreads();
  // a_f = sum_t x[f,t]*W1[t]; lane f owns row f
  float a = 0.f;
  #pragma unroll
  for (int t = 0; t < Tc; ++t) a += xs[tid * 25 + t] * w1s[t];
  af[tid] = a;
  __syncthreads();
  if (tid < Tc) {
    float l = 0.f, r2 = 0.f;
    #pragma unroll 8
    for (int f = 0; f < Fc; ++f) {
      l  += af[f] * W2[f * Tc + tid];
      r2 += w3s[f] * xs[f * 25 + tid];
    }
    lhs[(size_t)bn * Tc + tid] = l;
    rhs[(size_t)bn * Tc + tid] = r2;
  }
}

// ---------------------------------------------------------------------------
// Phase 2: sig[b,n,m] = sigmoid( sum_t lhs[b,n,t]*rhs[b,m,t] + bs[n,m] )
// 64x64 tile per block, K=24.
// ---------------------------------------------------------------------------
__global__ __launch_bounds__(256) void prodsig_kernel(
    const float* __restrict__ lhs, const float* __restrict__ rhs,
    const float* __restrict__ bs, float* __restrict__ sig) {
  int b = blockIdx.z;
  int n0 = blockIdx.y * 64, m0 = blockIdx.x * 64;
  __shared__ float Ls[64 * 25], Rs[64 * 25];
  int tid = threadIdx.x;
  const float* lp = lhs + ((size_t)b * Nc + n0) * Tc;
  const float* rp = rhs + ((size_t)b * Nc + m0) * Tc;
  for (int i = tid; i < 64 * Tc; i += 256) {
    Ls[(i / Tc) * 25 + i % Tc] = lp[i];
    Rs[(i / Tc) * 25 + i % Tc] = rp[i];
  }
  __syncthreads();
  int tx = tid % 16, ty = tid / 16;
  float acc[4][4] = {};
  for (int t = 0; t < Tc; ++t) {
    float av[4], bv[4];
    #pragma unroll
    for (int i = 0; i < 4; ++i) av[i] = Ls[(ty * 4 + i) * 25 + t];
    #pragma unroll
    for (int j = 0; j < 4; ++j) bv[j] = Rs[(tx * 4 + j) * 25 + t];
    #pragma unroll
    for (int i = 0; i < 4; ++i)
      #pragma unroll
      for (int j = 0; j < 4; ++j) acc[i][j] += av[i] * bv[j];
  }
  #pragma unroll
  for (int i = 0; i < 4; ++i) {
    int n = n0 + ty * 4 + i;
    #pragma unroll
    for (int j = 0; j < 4; ++j) {
      int m = m0 + tx * 4 + j;
      float p = acc[i][j] + bs[(size_t)n * Nc + m];
      sig[((size_t)b * Nc + n) * Nc + m] = 1.f / (1.f + expf(-p));
    }
  }
}

// ---------------------------------------------------------------------------
// Phase 3: Spre[b,i,j] = sum_kk Vs[i,kk] * sig[b,kk,j]
// 64x64 tile, K-step 16, fp32 4x4 per thread. LDS stride 68 keeps float4
// alignment and breaks pow-2 bank aliasing.
// ---------------------------------------------------------------------------
__global__ __launch_bounds__(256) void gemmvs_kernel(
    const float* __restrict__ Vs, const float* __restrict__ sig,
    float* __restrict__ S) {
  int b = blockIdx.z;
  int i0 = blockIdx.y * 64, j0 = blockIdx.x * 64;
  __shared__ float As[16 * 68];
  __shared__ float Bs[16 * 68];
  int tid = threadIdx.x;
  int tx = tid % 16, ty = tid / 16;
  float acc[4][4] = {};
  const float* sb = sig + (size_t)b * Nc * Nc;
  for (int kk0 = 0; kk0 < Nc; kk0 += 16) {
    {  // A tile: Vs[i0..+63][kk0..+15], transposed into As[k][i]
      int il = tid >> 2, kq = tid & 3;
      float4 v = *(const float4*)(Vs + (size_t)(i0 + il) * Nc + kk0 + kq * 4);
      As[(kq * 4 + 0) * 68 + il] = v.x;
      As[(kq * 4 + 1) * 68 + il] = v.y;
      As[(kq * 4 + 2) * 68 + il] = v.z;
      As[(kq * 4 + 3) * 68 + il] = v.w;
    }
    {  // B tile: sig[kk0..+15][j0..+63] direct
      int kl = tid >> 4, jq = tid & 15;
      float4 v = *(const float4*)(sb + (size_t)(kk0 + kl) * Nc + j0 + jq * 4);
      *(float4*)&Bs[kl * 68 + jq * 4] = v;
    }
    __syncthreads();
    #pragma unroll
    for (int k = 0; k < 16; ++k) {
      float4 a4 = *(const float4*)&As[k * 68 + ty * 4];
      float4 b4 = *(const float4*)&Bs[k * 68 + tx * 4];
      float av[4] = {a4.x, a4.y, a4.z, a4.w};
      float bv[4] = {b4.x, b4.y, b4.z, b4.w};
      #pragma unroll
      for (int i = 0; i < 4; ++i)
        #pragma unroll
        for (int j = 0; j < 4; ++j) acc[i][j] += av[i] * bv[j];
    }
    __syncthreads();
  }
  #pragma unroll
  for (int i = 0; i < 4; ++i) {
    float4 v = {acc[i][0], acc[i][1], acc[i][2], acc[i][3]};
    *(float4*)(S + ((size_t)b * Nc + i0 + ty * 4 + i) * Nc + j0 + tx * 4) = v;
  }
}

// ---------------------------------------------------------------------------
// Phase 4: softmax over axis=1 (the i index): per (b,j) column, in place.
// Thread owns one column; coalesced across j.
// ---------------------------------------------------------------------------
__global__ __launch_bounds__(256) void softmax_kernel(float* __restrict__ S) {
  int b = blockIdx.y;
  int j = blockIdx.x * 256 + threadIdx.x;
  float* sp = S + (size_t)b * Nc * Nc;
  float m = -INFINITY, l = 0.f;
  for (int i = 0; i < Nc; ++i) {
    float v = sp[(size_t)i * Nc + j];
    float mn = fmaxf(m, v);
    l = l * expf(m - mn) + expf(v - mn);
    m = mn;
  }
  float inv = 1.f / l;
  for (int i = 0; i < Nc; ++i) {
    float v = sp[(size_t)i * Nc + j];
    sp[(size_t)i * Nc + j] = expf(v - m) * inv;
  }
}

// ---------------------------------------------------------------------------
// Phase 5a (per k): r[b,m,c] = sum_n (cheb_k[n,m]*S[b,n,m]) * x[b,n,c]
// A is naturally [K=n][M=m] (no transpose); mask applied during staging.
// ---------------------------------------------------------------------------
__global__ __launch_bounds__(256) void gemmr_kernel(
    const float* __restrict__ cheb_k, const float* __restrict__ S,
    const float* __restrict__ x, float* __restrict__ r) {
  int b = blockIdx.z;
  int m0 = blockIdx.y * 64, c0 = blockIdx.x * 64;
  __shared__ float As[16 * 68];
  __shared__ float Bs[16 * 68];
  int tid = threadIdx.x;
  int tx = tid % 16, ty = tid / 16;
  float acc[4][4] = {};
  const float* Sb = S + (size_t)b * Nc * Nc;
  const float* xb = x + (size_t)b * Nc * Cc;
  for (int n0 = 0; n0 < Nc; n0 += 16) {
    {  // A tile: (cheb*S)[n0..+15][m0..+63]
      int nl = tid >> 4, mq = tid & 15;
      size_t off = (size_t)(n0 + nl) * Nc + m0 + mq * 4;
      float4 c4 = *(const float4*)(cheb_k + off);
      float4 s4 = *(const float4*)(Sb + off);
      float4 a4 = {c4.x * s4.x, c4.y * s4.y, c4.z * s4.z, c4.w * s4.w};
      *(float4*)&As[nl * 68 + mq * 4] = a4;
    }
    {  // B tile: x[b][n0..+15][c0..+63]
      int nl = tid >> 4, cq = tid & 15;
      float4 v = *(const float4*)(xb + (size_t)(n0 + nl) * Cc + c0 + cq * 4);
      *(float4*)&Bs[nl * 68 + cq * 4] = v;
    }
    __syncthreads();
    #pragma unroll
    for (int k = 0; k < 16; ++k) {
      float4 a4 = *(const float4*)&As[k * 68 + ty * 4];
      float4 b4 = *(const float4*)&Bs[k * 68 + tx * 4];
      float av[4] = {a4.x, a4.y, a4.z, a4.w};
      float bv[4] = {b4.x, b4.y, b4.z, b4.w};
      #pragma unroll
      for (int i = 0; i < 4; ++i)
        #pragma unroll
        for (int j = 0; j < 4; ++j) acc[i][j] += av[i] * bv[j];
    }
    __syncthreads();
  }
  #pragma unroll
  for (int i = 0; i < 4; ++i) {
    float4 v = {acc[i][0], acc[i][1], acc[i][2], acc[i][3]};
    *(float4*)(r + ((size_t)b * Nc + m0 + ty * 4 + i) * Cc + c0 + tx * 4) = v;
  }
}

// ---------------------------------------------------------------------------
// Phase 5b (per k): out[b,m,o,t] (+)= sum_f r[b,m,f,t] * Theta_k[f,o]
// mode 0: overwrite; 1: accumulate; 2: accumulate + relu (last k).
// Block = 384 threads: thread owns (t, o-group of 4); per f: 1 rs read +
// 1 float4 Theta read + 4 FMA.
// ---------------------------------------------------------------------------
__global__ __launch_bounds__(384) void theta_kernel(
    const float* __restrict__ r, const float* __restrict__ Theta_k,
    float* __restrict__ out, int mode) {
  int b = blockIdx.y;
  int mbase = blockIdx.x * 16;
  __shared__ float Th[Fc * FOc];  // 16 KB, [f][o]
  __shared__ float rs[Fc * 25];   // 6.4 KB, [f][t] padded
  int tid = threadIdx.x;
  for (int i = tid; i < Fc * FOc; i += 384) Th[i] = Theta_k[i];
  int t = tid % Tc;        // 0..23
  int og = tid / Tc;       // 0..15
  for (int ml = 0; ml < 16; ++ml) {
    int m = mbase + ml;
    const float* rp = r + ((size_t)b * Nc + m) * Cc;
    __syncthreads();  // protect rs (and Th on first iter)
    for (int i = tid; i < Cc; i += 384) rs[(i / Tc) * 25 + i % Tc] = rp[i];
    __syncthreads();
    float acc[4] = {0.f, 0.f, 0.f, 0.f};
    #pragma unroll 8
    for (int f = 0; f < Fc; ++f) {
      float rv = rs[f * 25 + t];
      float4 th = *(const float4*)&Th[f * FOc + og * 4];
      acc[0] += rv * th.x;
      acc[1] += rv * th.y;
      acc[2] += rv * th.z;
      acc[3] += rv * th.w;
    }
    size_t obase = (((size_t)b * Nc + m) * FOc + og * 4) * Tc + t;
    #pragma unroll
    for (int j = 0; j < 4; ++j) {
      size_t oaddr = obase + (size_t)j * Tc;
      float prev = (mode == 0) ? 0.f : out[oaddr];
      float v = prev + acc[j];
      if (mode == 2) v = fmaxf(v, 0.f);
      out[oaddr] = v;
    }
  }
}

// ---------------------------------------------------------------------------
extern "C" void kernel_launch(void* const* d_in, const int* in_sizes, int n_in,
                              void* d_out, int out_size, void* d_ws, size_t ws_size,
                              hipStream_t stream) {
  const float* x     = (const float*)d_in[0];  // (B,N,F,T)
  const float* W1    = (const float*)d_in[1];  // (T)
  const float* W2    = (const float*)d_in[2];  // (F,T)
  const float* W3    = (const float*)d_in[3];  // (F)
  const float* bs    = (const float*)d_in[4];  // (1,N,N)
  const float* Vs    = (const float*)d_in[5];  // (N,N)
  const float* cheb  = (const float*)d_in[6];  // (K,N,N)
  const float* Theta = (const float*)d_in[7];  // (K,F,FO)
  float* out = (float*)d_out;                  // (B,N,FO,T) fp32

  float* ws = (float*)d_ws;
  float* lhs  = ws;                                   // B*N*T
  float* rhs  = lhs + (size_t)Bc * Nc * Tc;           // B*N*T
  float* sig  = rhs + (size_t)Bc * Nc * Tc;           // B*N*N
  float* S    = sig + (size_t)Bc * Nc * Nc;           // B*N*N
  float* rbuf = S + (size_t)Bc * Nc * Nc;             // B*N*C

  prep_kernel<<<Bc * Nc, 64, 0, stream>>>(x, W1, W2, W3, lhs, rhs);
  prodsig_kernel<<<dim3(Nc / 64, Nc / 64, Bc), 256, 0, stream>>>(lhs, rhs, bs, sig);
  gemmvs_kernel<<<dim3(Nc / 64, Nc / 64, Bc), 256, 0, stream>>>(Vs, sig, S);
  softmax_kernel<<<dim3(Nc / 256, Bc), 256, 0, stream>>>(S);
  for (int k = 0; k < Kc; ++k) {
    gemmr_kernel<<<dim3(Cc / 64, Nc / 64, Bc), 256, 0, stream>>>(
        cheb + (size_t)k * Nc * Nc, S, x, rbuf);
    int mode = (k == 0) ? 0 : ((k == Kc - 1) ? 2 : 1);
    theta_kernel<<<dim3(Nc / 16, Bc), 384, 0, stream>>>(
        rbuf, Theta + (size_t)k * Fc * FOc, out, mode);
  }
}

// Round 2
// 908.262 us; speedup vs baseline: 3.5590x; 3.5590x over previous
//
#include <hip/hip_runtime.h>
#include <math.h>

// Problem constants: B=16, N=1024, F=64, T=24, K=3, FO=64
#define Bc 16
#define Nc 1024
#define Fc 64
#define Tc 24
#define Kc 3
#define FOc 64
#define Cc (Fc*Tc)   // 1536

typedef __attribute__((ext_vector_type(8))) short short8;   // 8 bf16 (4 VGPRs)
typedef __attribute__((ext_vector_type(8))) unsigned short u16x8;
typedef __attribute__((ext_vector_type(4))) float f32x4;

__device__ __forceinline__ unsigned short f2bf(float f) {
  unsigned u = __float_as_uint(f);
  u += 0x7fff + ((u >> 16) & 1);   // round-to-nearest-even
  return (unsigned short)(u >> 16);
}
__device__ __forceinline__ float bf2f(unsigned short h) {
  return __uint_as_float((unsigned)h << 16);
}

// async global->LDS, 16B per lane; LDS dest = wave-uniform base + lane*16
#define GLL16(g, l) __builtin_amdgcn_global_load_lds( \
    (const __attribute__((address_space(1))) void*)(g), \
    (__attribute__((address_space(3))) void*)(l), 16, 0, 0)

__device__ __forceinline__ f32x4 mfma16(short8 a, short8 b, f32x4 c) {
  return __builtin_amdgcn_mfma_f32_16x16x32_bf16(a, b, c, 0, 0, 0);
}

// ---------------------------------------------------------------------------
// Phase 1: lhs[b,n,t'] = sum_f (sum_t x*W1) * W2 ; rhs[b,n,t] = sum_f W3*x
// ---------------------------------------------------------------------------
__global__ __launch_bounds__(64) void prep_kernel(
    const float* __restrict__ x, const float* __restrict__ W1,
    const float* __restrict__ W2, const float* __restrict__ W3,
    float* __restrict__ lhs, float* __restrict__ rhs) {
  int bn = blockIdx.x;
  int tid = threadIdx.x;
  __shared__ float xs[Fc * 25];
  __shared__ float w1s[Tc];
  __shared__ float w3s[Fc];
  __shared__ float af[Fc];
  const float* xp = x + (size_t)bn * Cc;
  for (int i = tid; i < Cc; i += 64) xs[(i / Tc) * 25 + (i % Tc)] = xp[i];
  if (tid < Tc) w1s[tid] = W1[tid];
  w3s[tid] = W3[tid];
  __syncthreads();
  float a = 0.f;
  #pragma unroll
  for (int t = 0; t < Tc; ++t) a += xs[tid * 25 + t] * w1s[t];
  af[tid] = a;
  __syncthreads();
  if (tid < Tc) {
    float l = 0.f, r2 = 0.f;
    #pragma unroll 8
    for (int f = 0; f < Fc; ++f) {
      l  += af[f] * W2[f * Tc + tid];
      r2 += w3s[f] * xs[f * 25 + tid];
    }
    lhs[(size_t)bn * Tc + tid] = l;
    rhs[(size_t)bn * Tc + tid] = r2;
  }
}

// ---------------------------------------------------------------------------
// Phase 2: sigT[b][p][q] = bf16(sigmoid(dot(lhs[b][q],rhs[b][p]) + bs[q][p]))
// (transposed sigmoid matrix, K-contiguous for the ST GEMM)
// ---------------------------------------------------------------------------
__global__ __launch_bounds__(256) void prodsigT_kernel(
    const float* __restrict__ lhs, const float* __restrict__ rhs,
    const float* __restrict__ bs, unsigned short* __restrict__ sigT) {
  int b = blockIdx.z;
  int p0 = blockIdx.y * 64, q0 = blockIdx.x * 64;
  __shared__ float Ls[64 * 25], Rs[64 * 25], Bt[64 * 65];
  int tid = threadIdx.x;
  const float* lp = lhs + ((size_t)b * Nc + q0) * Tc;
  const float* rp = rhs + ((size_t)b * Nc + p0) * Tc;
  for (int i = tid; i < 64 * Tc; i += 256) {
    Ls[(i / Tc) * 25 + i % Tc] = lp[i];
    Rs[(i / Tc) * 25 + i % Tc] = rp[i];
  }
  for (int i = tid; i < 1024; i += 256) {  // bias tile bs[q][p] -> Bt[q][p]
    int qr = i >> 4, pc = (i & 15) * 4;
    *(float4*)&Bt[qr * 65 + pc] = *(const float4*)&bs[(size_t)(q0 + qr) * Nc + p0 + pc];
  }
  __syncthreads();
  int tx = tid % 16, ty = tid / 16;
  float acc[4][4] = {};
  for (int t = 0; t < Tc; ++t) {
    float rv[4], lv[4];
    #pragma unroll
    for (int i = 0; i < 4; ++i) rv[i] = Rs[(ty * 4 + i) * 25 + t];
    #pragma unroll
    for (int j = 0; j < 4; ++j) lv[j] = Ls[(tx * 4 + j) * 25 + t];
    #pragma unroll
    for (int i = 0; i < 4; ++i)
      #pragma unroll
      for (int j = 0; j < 4; ++j) acc[i][j] += rv[i] * lv[j];
  }
  #pragma unroll
  for (int i = 0; i < 4; ++i) {
    int p = p0 + ty * 4 + i;
    ushort4 o;
    float v0 = acc[i][0] + Bt[(tx * 4 + 0) * 65 + ty * 4 + i];
    float v1 = acc[i][1] + Bt[(tx * 4 + 1) * 65 + ty * 4 + i];
    float v2 = acc[i][2] + Bt[(tx * 4 + 2) * 65 + ty * 4 + i];
    float v3 = acc[i][3] + Bt[(tx * 4 + 3) * 65 + ty * 4 + i];
    o.x = f2bf(1.f / (1.f + __expf(-v0)));
    o.y = f2bf(1.f / (1.f + __expf(-v1)));
    o.z = f2bf(1.f / (1.f + __expf(-v2)));
    o.w = f2bf(1.f / (1.f + __expf(-v3)));
    *(ushort4*)&sigT[((size_t)b * Nc + p) * Nc + q0 + tx * 4] = o;
  }
}

// ---------------------------------------------------------------------------
// Vs fp32 -> bf16 (already K-contiguous [i][kk])
// ---------------------------------------------------------------------------
__global__ __launch_bounds__(256) void cvt_vs_kernel(
    const float* __restrict__ Vs, unsigned short* __restrict__ Vsbf) {
  int i = (blockIdx.x * 256 + threadIdx.x) * 4;
  float4 v = *(const float4*)&Vs[i];
  ushort4 o;
  o.x = f2bf(v.x); o.y = f2bf(v.y); o.z = f2bf(v.z); o.w = f2bf(v.w);
  *(ushort4*)&Vsbf[i] = o;
}

// ---------------------------------------------------------------------------
// chebT[k][m][n] = cheb[k][n][m] (fp32 transpose, LDS tiles)
// ---------------------------------------------------------------------------
__global__ __launch_bounds__(256) void chebT_kernel(
    const float* __restrict__ cheb, float* __restrict__ chebT) {
  int k = blockIdx.z;
  int n0 = blockIdx.y * 64, m0 = blockIdx.x * 64;
  __shared__ float t[64 * 65];
  const float* src = cheb + (size_t)k * Nc * Nc;
  float* dst = chebT + (size_t)k * Nc * Nc;
  int tid = threadIdx.x;
  #pragma unroll
  for (int s = 0; s < 4; ++s) {
    int nr = (tid >> 4) + s * 16, mc = (tid & 15) * 4;
    float4 v = *(const float4*)&src[(size_t)(n0 + nr) * Nc + m0 + mc];
    t[(mc + 0) * 65 + nr] = v.x;
    t[(mc + 1) * 65 + nr] = v.y;
    t[(mc + 2) * 65 + nr] = v.z;
    t[(mc + 3) * 65 + nr] = v.w;
  }
  __syncthreads();
  #pragma unroll
  for (int s = 0; s < 4; ++s) {
    int mr = (tid >> 4) + s * 16, nc = (tid & 15) * 4;
    float4 v = {t[mr * 65 + nc], t[mr * 65 + nc + 1], t[mr * 65 + nc + 2], t[mr * 65 + nc + 3]};
    *(float4*)&dst[(size_t)(m0 + mr) * Nc + n0 + nc] = v;
  }
}

// ---------------------------------------------------------------------------
// xT[b][c][n] = bf16(x[b][n][c]) (transpose + cvt, LDS tiles)
// ---------------------------------------------------------------------------
__global__ __launch_bounds__(256) void xT_kernel(
    const float* __restrict__ x, unsigned short* __restrict__ xT) {
  int b = blockIdx.z;
  int n0 = blockIdx.y * 64, c0 = blockIdx.x * 64;
  __shared__ unsigned short t[64 * 65];
  const float* src = x + (size_t)b * Nc * Cc;
  unsigned short* dst = xT + (size_t)b * Cc * Nc;
  int tid = threadIdx.x;
  #pragma unroll
  for (int s = 0; s < 4; ++s) {
    int nr = (tid >> 4) + s * 16, cc = (tid & 15) * 4;
    float4 v = *(const float4*)&src[(size_t)(n0 + nr) * Cc + c0 + cc];
    t[(cc + 0) * 65 + nr] = f2bf(v.x);
    t[(cc + 1) * 65 + nr] = f2bf(v.y);
    t[(cc + 2) * 65 + nr] = f2bf(v.z);
    t[(cc + 3) * 65 + nr] = f2bf(v.w);
  }
  __syncthreads();
  #pragma unroll
  for (int s = 0; s < 4; ++s) {
    int cr = (tid >> 4) + s * 16, nc = (tid & 15) * 4;
    ushort4 o;
    o.x = t[cr * 65 + nc];
    o.y = t[cr * 65 + nc + 1];
    o.z = t[cr * 65 + nc + 2];
    o.w = t[cr * 65 + nc + 3];
    *(ushort4*)&dst[(size_t)(c0 + cr) * Nc + n0 + nc] = o;
  }
}

// ---------------------------------------------------------------------------
// MFMA GEMM (m97 structure): C[m][n] = sum_k A[m][k]*B[n][k], bf16 in/out,
// fp32 accumulate. 128x128 tile, 256 thr (4 waves), K-step 32,
// global_load_lds width-16 staging. A rows = blockIdx.y, B rows = blockIdx.x.
// ---------------------------------------------------------------------------
__global__ __launch_bounds__(256) void mfma_gemm_bt(
    const unsigned short* __restrict__ A, const unsigned short* __restrict__ B,
    unsigned short* __restrict__ C, int K, int CN,
    long long Abatch, long long Bbatch, long long Cbatch) {
  __shared__ unsigned short As[128 * 32];
  __shared__ unsigned short Bs[128 * 32];
  int b = blockIdx.z;
  int tid = threadIdx.x;
  int wave = tid >> 6, lane = tid & 63;
  const unsigned short* Ag = A + (size_t)b * Abatch + (size_t)blockIdx.y * 128 * K;
  const unsigned short* Bg = B + (size_t)b * Bbatch + (size_t)blockIdx.x * 128 * K;
  // staging: wave w covers rows [w*32, w*32+32); two 1KB wave-calls each for A,B
  int srow = wave * 32 + (lane >> 2);
  int scol = (lane & 3) * 8;
  const unsigned short* ag0 = Ag + (size_t)srow * K + scol;
  const unsigned short* ag1 = ag0 + (size_t)16 * K;
  const unsigned short* bg0 = Bg + (size_t)srow * K + scol;
  const unsigned short* bg1 = bg0 + (size_t)16 * K;
  unsigned short* as0 = As + (wave * 32) * 32;
  unsigned short* as1 = As + (wave * 32 + 16) * 32;
  unsigned short* bs0 = Bs + (wave * 32) * 32;
  unsigned short* bs1 = Bs + (wave * 32 + 16) * 32;
  // compute: wave -> 64x64 quadrant
  int rw = (wave >> 1) * 64, cw = (wave & 1) * 64;
  int frow = lane & 15, fk = (lane >> 4) * 8;
  f32x4 zero = {0.f, 0.f, 0.f, 0.f};
  f32x4 acc[4][4];
  #pragma unroll
  for (int i = 0; i < 4; ++i)
    #pragma unroll
    for (int j = 0; j < 4; ++j) acc[i][j] = zero;

  for (int k0 = 0; k0 < K; k0 += 32) {
    GLL16(ag0, as0); GLL16(ag1, as1);
    GLL16(bg0, bs0); GLL16(bg1, bs1);
    ag0 += 32; ag1 += 32; bg0 += 32; bg1 += 32;
    __syncthreads();   // drains vmcnt before barrier -> LDS tiles ready
    short8 afr[4], bfr[4];
    #pragma unroll
    for (int i = 0; i < 4; ++i)
      afr[i] = *(const short8*)&As[(rw + i * 16 + frow) * 32 + fk];
    #pragma unroll
    for (int j = 0; j < 4; ++j)
      bfr[j] = *(const short8*)&Bs[(cw + j * 16 + frow) * 32 + fk];
    #pragma unroll
    for (int i = 0; i < 4; ++i)
      #pragma unroll
      for (int j = 0; j < 4; ++j)
        acc[i][j] = mfma16(afr[i], bfr[j], acc[i][j]);
    __syncthreads();   // protect LDS before next stage
  }
  // epilogue: C/D layout col=lane&15, row=(lane>>4)*4+e
  unsigned short* Cg = C + (size_t)b * Cbatch + (size_t)blockIdx.y * 128 * CN
                       + (size_t)blockIdx.x * 128;
  int q = lane >> 4, cl = lane & 15;
  #pragma unroll
  for (int i = 0; i < 4; ++i)
    #pragma unroll
    for (int j = 0; j < 4; ++j)
      #pragma unroll
      for (int e = 0; e < 4; ++e)
        Cg[(size_t)(rw + i * 16 + q * 4 + e) * CN + cw + j * 16 + cl] =
            f2bf(acc[i][j][e]);
}

// ---------------------------------------------------------------------------
// Softmax over contiguous dim of ST rows (= axis 1 of S), in place, bf16.
// One wave per row of 1024.
// ---------------------------------------------------------------------------
__global__ __launch_bounds__(256) void softmax_rows_kernel(unsigned short* __restrict__ ST) {
  int row = (blockIdx.x * 256 + threadIdx.x) >> 6;
  int lane = threadIdx.x & 63;
  unsigned short* rp = ST + (size_t)row * Nc + lane * 16;
  u16x8 r0 = *(const u16x8*)rp;
  u16x8 r1 = *(const u16x8*)(rp + 8);
  float v[16];
  #pragma unroll
  for (int s = 0; s < 8; ++s) { v[s] = bf2f(r0[s]); v[8 + s] = bf2f(r1[s]); }
  float m = -INFINITY;
  #pragma unroll
  for (int s = 0; s < 16; ++s) m = fmaxf(m, v[s]);
  #pragma unroll
  for (int off = 32; off; off >>= 1) m = fmaxf(m, __shfl_xor(m, off));
  float sum = 0.f;
  #pragma unroll
  for (int s = 0; s < 16; ++s) { v[s] = __expf(v[s] - m); sum += v[s]; }
  #pragma unroll
  for (int off = 32; off; off >>= 1) sum += __shfl_xor(sum, off);
  float inv = 1.f / sum;
  #pragma unroll
  for (int s = 0; s < 8; ++s) { r0[s] = f2bf(v[s] * inv); r1[s] = f2bf(v[8 + s] * inv); }
  *(u16x8*)rp = r0;
  *(u16x8*)(rp + 8) = r1;
}

// ---------------------------------------------------------------------------
// Mask (per k): Abf[b][m][n] = bf16(chebT[k][m][n] * ST[b][m][n]), elementwise
// ---------------------------------------------------------------------------
__global__ __launch_bounds__(256) void mask_kernel(
    const float* __restrict__ chebTk, const unsigned short* __restrict__ ST,
    unsigned short* __restrict__ Abf) {
  size_t idx = ((size_t)blockIdx.x * 256 + threadIdx.x) * 8;
  size_t b = idx >> 20;
  size_t off = idx & ((1u << 20) - 1);
  const float* cp = chebTk + off;
  const unsigned short* sp = ST + (b << 20) + off;
  u16x8 s = *(const u16x8*)sp;
  float4 c0 = *(const float4*)cp;
  float4 c1 = *(const float4*)(cp + 4);
  u16x8 o;
  o[0] = f2bf(c0.x * bf2f(s[0]));
  o[1] = f2bf(c0.y * bf2f(s[1]));
  o[2] = f2bf(c0.z * bf2f(s[2]));
  o[3] = f2bf(c0.w * bf2f(s[3]));
  o[4] = f2bf(c1.x * bf2f(s[4]));
  o[5] = f2bf(c1.y * bf2f(s[5]));
  o[6] = f2bf(c1.z * bf2f(s[6]));
  o[7] = f2bf(c1.w * bf2f(s[7]));
  *(u16x8*)(Abf + (b << 20) + off) = o;
}

// ---------------------------------------------------------------------------
// Theta contraction (per k): out[b,m,o,t] (+)= sum_f r[b,m,f,t]*Theta_k[f,o]
// r is bf16 now. mode 0: overwrite; 1: accumulate; 2: accumulate+relu.
// ---------------------------------------------------------------------------
__global__ __launch_bounds__(384) void theta_kernel(
    const unsigned short* __restrict__ r, const float* __restrict__ Theta_k,
    float* __restrict__ out, int mode) {
  int b = blockIdx.y;
  int mbase = blockIdx.x * 16;
  __shared__ float Th[Fc * FOc];
  __shared__ float rs[Fc * 25];
  int tid = threadIdx.x;
  for (int i = tid; i < Fc * FOc; i += 384) Th[i] = Theta_k[i];
  int t = tid % Tc;
  int og = tid / Tc;
  for (int ml = 0; ml < 16; ++ml) {
    int m = mbase + ml;
    const unsigned short* rp = r + ((size_t)b * Nc + m) * Cc;
    __syncthreads();
    for (int i = tid; i < Cc; i += 384) rs[(i / Tc) * 25 + i % Tc] = bf2f(rp[i]);
    __syncthreads();
    float acc[4] = {0.f, 0.f, 0.f, 0.f};
    #pragma unroll 8
    for (int f = 0; f < Fc; ++f) {
      float rv = rs[f * 25 + t];
      float4 th = *(const float4*)&Th[f * FOc + og * 4];
      acc[0] += rv * th.x;
      acc[1] += rv * th.y;
      acc[2] += rv * th.z;
      acc[3] += rv * th.w;
    }
    size_t obase = (((size_t)b * Nc + m) * FOc + og * 4) * Tc + t;
    #pragma unroll
    for (int j = 0; j < 4; ++j) {
      size_t oaddr = obase + (size_t)j * Tc;
      float prev = (mode == 0) ? 0.f : out[oaddr];
      float v = prev + acc[j];
      if (mode == 2) v = fmaxf(v, 0.f);
      out[oaddr] = v;
    }
  }
}

// ---------------------------------------------------------------------------
extern "C" void kernel_launch(void* const* d_in, const int* in_sizes, int n_in,
                              void* d_out, int out_size, void* d_ws, size_t ws_size,
                              hipStream_t stream) {
  const float* x     = (const float*)d_in[0];
  const float* W1    = (const float*)d_in[1];
  const float* W2    = (const float*)d_in[2];
  const float* W3    = (const float*)d_in[3];
  const float* bs    = (const float*)d_in[4];
  const float* Vs    = (const float*)d_in[5];
  const float* cheb  = (const float*)d_in[6];
  const float* Theta = (const float*)d_in[7];
  float* out = (float*)d_out;

  char* w = (char*)d_ws;
  float* lhs = (float*)w;               w += (size_t)Bc * Nc * Tc * 4;       // 1.57 MB
  float* rhs = (float*)w;               w += (size_t)Bc * Nc * Tc * 4;       // 1.57 MB
  unsigned short* sigT = (unsigned short*)w;  w += (size_t)Bc * Nc * Nc * 2; // 33.6 MB
  unsigned short* ST   = (unsigned short*)w;  w += (size_t)Bc * Nc * Nc * 2; // 33.6 MB
  unsigned short* xT   = (unsigned short*)w;  w += (size_t)Bc * Cc * Nc * 2; // 50.3 MB
  unsigned short* Vsbf = (unsigned short*)w;  w += (size_t)Nc * Nc * 2;      //  2.1 MB
  float* chebT = (float*)w;             w += (size_t)Kc * Nc * Nc * 4;       // 12.6 MB
  unsigned short* Abf  = (unsigned short*)w;  w += (size_t)Bc * Nc * Nc * 2; // 33.6 MB
  unsigned short* rbuf = (unsigned short*)w;  w += (size_t)Bc * Nc * Cc * 2; // 50.3 MB
  // total ~219 MB (< the 238 MB the fp32 version used)

  prep_kernel<<<Bc * Nc, 64, 0, stream>>>(x, W1, W2, W3, lhs, rhs);
  prodsigT_kernel<<<dim3(Nc / 64, Nc / 64, Bc), 256, 0, stream>>>(lhs, rhs, bs, sigT);
  cvt_vs_kernel<<<Nc * Nc / 1024, 256, 0, stream>>>(Vs, Vsbf);
  chebT_kernel<<<dim3(Nc / 64, Nc / 64, Kc), 256, 0, stream>>>(cheb, chebT);
  xT_kernel<<<dim3(Cc / 64, Nc / 64, Bc), 256, 0, stream>>>(x, xT);
  // ST[b][j][i] = sum_kk sigT[b][j][kk] * Vs[i][kk]
  mfma_gemm_bt<<<dim3(Nc / 128, Nc / 128, Bc), 256, 0, stream>>>(
      sigT, Vsbf, ST, Nc, Nc,
      (long long)Nc * Nc, 0LL, (long long)Nc * Nc);
  softmax_rows_kernel<<<Bc * Nc / 4, 256, 0, stream>>>(ST);
  for (int k = 0; k < Kc; ++k) {
    mask_kernel<<<(Bc * Nc * Nc / 8) / 256, 256, 0, stream>>>(
        chebT + (size_t)k * Nc * Nc, ST, Abf);
    // r[b][m][c] = sum_n Abf[b][m][n] * xT[b][c][n]
    mfma_gemm_bt<<<dim3(Cc / 128, Nc / 128, Bc), 256, 0, stream>>>(
        Abf, xT, rbuf, Nc, Cc,
        (long long)Nc * Nc, (long long)Cc * Nc, (long long)Nc * Cc);
    int mode = (k == 0) ? 0 : ((k == Kc - 1) ? 2 : 1);
    theta_kernel<<<dim3(Nc / 16, Bc), 384, 0, stream>>>(
        rbuf, Theta + (size_t)k * Fc * FOc, out, mode);
  }
}

// Round 3
// 659.819 us; speedup vs baseline: 4.8991x; 1.3765x over previous
//
#include <hip/hip_runtime.h>
#include <math.h>

// Problem constants: B=16, N=1024, F=64, T=24, K=3, FO=64
#define Bc 16
#define Nc 1024
#define Fc 64
#define Tc 24
#define Kc 3
#define FOc 64
#define Cc (Fc*Tc)      // 1536
#define KKc (Kc*Nc)     // 3072 = fused reduction length

typedef __attribute__((ext_vector_type(8))) short short8;   // 8 bf16 (4 VGPRs)
typedef __attribute__((ext_vector_type(8))) unsigned short u16x8;
typedef __attribute__((ext_vector_type(4))) float f32x4;

__device__ __forceinline__ unsigned short f2bf(float f) {
  unsigned u = __float_as_uint(f);
  u += 0x7fff + ((u >> 16) & 1);   // round-to-nearest-even
  return (unsigned short)(u >> 16);
}
__device__ __forceinline__ float bf2f(unsigned short h) {
  return __uint_as_float((unsigned)h << 16);
}

#define GLL16(g, l) __builtin_amdgcn_global_load_lds( \
    (const __attribute__((address_space(1))) void*)(g), \
    (__attribute__((address_space(3))) void*)(l), 16, 0, 0)

__device__ __forceinline__ f32x4 mfma16(short8 a, short8 b, f32x4 c) {
  return __builtin_amdgcn_mfma_f32_16x16x32_bf16(a, b, c, 0, 0, 0);
}

// ---------------------------------------------------------------------------
// Phase 1: lhs[b,n,t'] = sum_f (sum_t x*W1) * W2 ; rhs[b,n,t] = sum_f W3*x
// ---------------------------------------------------------------------------
__global__ __launch_bounds__(64) void prep_kernel(
    const float* __restrict__ x, const float* __restrict__ W1,
    const float* __restrict__ W2, const float* __restrict__ W3,
    float* __restrict__ lhs, float* __restrict__ rhs) {
  int bn = blockIdx.x;
  int tid = threadIdx.x;
  __shared__ float xs[Fc * 25];
  __shared__ float w1s[Tc];
  __shared__ float w3s[Fc];
  __shared__ float af[Fc];
  const float* xp = x + (size_t)bn * Cc;
  for (int i = tid; i < Cc; i += 64) xs[(i / Tc) * 25 + (i % Tc)] = xp[i];
  if (tid < Tc) w1s[tid] = W1[tid];
  w3s[tid] = W3[tid];
  __syncthreads();
  float a = 0.f;
  #pragma unroll
  for (int t = 0; t < Tc; ++t) a += xs[tid * 25 + t] * w1s[t];
  af[tid] = a;
  __syncthreads();
  if (tid < Tc) {
    float l = 0.f, r2 = 0.f;
    #pragma unroll 8
    for (int f = 0; f < Fc; ++f) {
      l  += af[f] * W2[f * Tc + tid];
      r2 += w3s[f] * xs[f * 25 + tid];
    }
    lhs[(size_t)bn * Tc + tid] = l;
    rhs[(size_t)bn * Tc + tid] = r2;
  }
}

// ---------------------------------------------------------------------------
// Phase 2: sigT[b][p][q] = bf16(sigmoid(dot(lhs[b][q],rhs[b][p]) + bs[q][p]))
// ---------------------------------------------------------------------------
__global__ __launch_bounds__(256) void prodsigT_kernel(
    const float* __restrict__ lhs, const float* __restrict__ rhs,
    const float* __restrict__ bs, unsigned short* __restrict__ sigT) {
  int b = blockIdx.z;
  int p0 = blockIdx.y * 64, q0 = blockIdx.x * 64;
  __shared__ float Ls[64 * 25], Rs[64 * 25], Bt[64 * 65];
  int tid = threadIdx.x;
  const float* lp = lhs + ((size_t)b * Nc + q0) * Tc;
  const float* rp = rhs + ((size_t)b * Nc + p0) * Tc;
  for (int i = tid; i < 64 * Tc; i += 256) {
    Ls[(i / Tc) * 25 + i % Tc] = lp[i];
    Rs[(i / Tc) * 25 + i % Tc] = rp[i];
  }
  for (int i = tid; i < 1024; i += 256) {
    int qr = i >> 4, pc = (i & 15) * 4;
    *(float4*)&Bt[qr * 65 + pc] = *(const float4*)&bs[(size_t)(q0 + qr) * Nc + p0 + pc];
  }
  __syncthreads();
  int tx = tid % 16, ty = tid / 16;
  float acc[4][4] = {};
  for (int t = 0; t < Tc; ++t) {
    float rv[4], lv[4];
    #pragma unroll
    for (int i = 0; i < 4; ++i) rv[i] = Rs[(ty * 4 + i) * 25 + t];
    #pragma unroll
    for (int j = 0; j < 4; ++j) lv[j] = Ls[(tx * 4 + j) * 25 + t];
    #pragma unroll
    for (int i = 0; i < 4; ++i)
      #pragma unroll
      for (int j = 0; j < 4; ++j) acc[i][j] += rv[i] * lv[j];
  }
  #pragma unroll
  for (int i = 0; i < 4; ++i) {
    int p = p0 + ty * 4 + i;
    ushort4 o;
    float v0 = acc[i][0] + Bt[(tx * 4 + 0) * 65 + ty * 4 + i];
    float v1 = acc[i][1] + Bt[(tx * 4 + 1) * 65 + ty * 4 + i];
    float v2 = acc[i][2] + Bt[(tx * 4 + 2) * 65 + ty * 4 + i];
    float v3 = acc[i][3] + Bt[(tx * 4 + 3) * 65 + ty * 4 + i];
    o.x = f2bf(1.f / (1.f + __expf(-v0)));
    o.y = f2bf(1.f / (1.f + __expf(-v1)));
    o.z = f2bf(1.f / (1.f + __expf(-v2)));
    o.w = f2bf(1.f / (1.f + __expf(-v3)));
    *(ushort4*)&sigT[((size_t)b * Nc + p) * Nc + q0 + tx * 4] = o;
  }
}

// ---------------------------------------------------------------------------
// Vs fp32 -> bf16
// ---------------------------------------------------------------------------
__global__ __launch_bounds__(256) void cvt_vs_kernel(
    const float* __restrict__ Vs, unsigned short* __restrict__ Vsbf) {
  int i = (blockIdx.x * 256 + threadIdx.x) * 4;
  float4 v = *(const float4*)&Vs[i];
  ushort4 o;
  o.x = f2bf(v.x); o.y = f2bf(v.y); o.z = f2bf(v.z); o.w = f2bf(v.w);
  *(ushort4*)&Vsbf[i] = o;
}

// ---------------------------------------------------------------------------
// chebT[k][m][n] = cheb[k][n][m] (fp32 transpose)
// ---------------------------------------------------------------------------
__global__ __launch_bounds__(256) void chebT_kernel(
    const float* __restrict__ cheb, float* __restrict__ chebT) {
  int k = blockIdx.z;
  int n0 = blockIdx.y * 64, m0 = blockIdx.x * 64;
  __shared__ float t[64 * 65];
  const float* src = cheb + (size_t)k * Nc * Nc;
  float* dst = chebT + (size_t)k * Nc * Nc;
  int tid = threadIdx.x;
  #pragma unroll
  for (int s = 0; s < 4; ++s) {
    int nr = (tid >> 4) + s * 16, mc = (tid & 15) * 4;
    float4 v = *(const float4*)&src[(size_t)(n0 + nr) * Nc + m0 + mc];
    t[(mc + 0) * 65 + nr] = v.x;
    t[(mc + 1) * 65 + nr] = v.y;
    t[(mc + 2) * 65 + nr] = v.z;
    t[(mc + 3) * 65 + nr] = v.w;
  }
  __syncthreads();
  #pragma unroll
  for (int s = 0; s < 4; ++s) {
    int mr = (tid >> 4) + s * 16, nc = (tid & 15) * 4;
    float4 v = {t[mr * 65 + nc], t[mr * 65 + nc + 1], t[mr * 65 + nc + 2], t[mr * 65 + nc + 3]};
    *(float4*)&dst[(size_t)(m0 + mr) * Nc + n0 + nc] = v;
  }
}

// ---------------------------------------------------------------------------
// xt2[b][n][t][f] = bf16(x[b][n][f][t]) — per-row 64x24 transpose via LDS.
// One wave per (b,n) row; 4 rows per block.
// ---------------------------------------------------------------------------
__global__ __launch_bounds__(256) void xt2_kernel(
    const float* __restrict__ x, unsigned short* __restrict__ xt2) {
  __shared__ unsigned short ld[4 * Cc];
  int w = threadIdx.x >> 6, lane = threadIdx.x & 63;
  size_t n = (size_t)blockIdx.x * 4 + w;
  const float* xp = x + n * Cc;
  unsigned short* op = xt2 + n * Cc;
  #pragma unroll
  for (int j = 0; j < 24; ++j) {
    int i = j * 64 + lane;
    int f = i / 24, t = i - f * 24;
    ld[w * Cc + t * 64 + f] = f2bf(xp[i]);
  }
  __syncthreads();
  #pragma unroll
  for (int j = 0; j < 24; ++j)
    op[j * 64 + lane] = ld[w * Cc + j * 64 + lane];
}

// ---------------------------------------------------------------------------
// tcat[(k*64+o)][f] = bf16(Theta[k][f][o]); 256 rows alloc, rows>=192 zeroed
// ---------------------------------------------------------------------------
__global__ __launch_bounds__(256) void tcat_kernel(
    const float* __restrict__ Theta, unsigned short* __restrict__ tcat) {
  int i = blockIdx.x * 256 + threadIdx.x;   // 0..16383
  int m2 = i >> 6, f = i & 63;
  int k = m2 >> 6, o = m2 & 63;
  tcat[i] = (m2 < 192) ? f2bf(Theta[((size_t)k * Fc + f) * FOc + o])
                       : (unsigned short)0;
}

// ---------------------------------------------------------------------------
// Softmax over contiguous dim of ST rows (= axis 1 of S), in place, bf16.
// ---------------------------------------------------------------------------
__global__ __launch_bounds__(256) void softmax_rows_kernel(unsigned short* __restrict__ ST) {
  int row = (blockIdx.x * 256 + threadIdx.x) >> 6;
  int lane = threadIdx.x & 63;
  unsigned short* rp = ST + (size_t)row * Nc + lane * 16;
  u16x8 r0 = *(const u16x8*)rp;
  u16x8 r1 = *(const u16x8*)(rp + 8);
  float v[16];
  #pragma unroll
  for (int s = 0; s < 8; ++s) { v[s] = bf2f(r0[s]); v[8 + s] = bf2f(r1[s]); }
  float m = -INFINITY;
  #pragma unroll
  for (int s = 0; s < 16; ++s) m = fmaxf(m, v[s]);
  #pragma unroll
  for (int off = 32; off; off >>= 1) m = fmaxf(m, __shfl_xor(m, off));
  float sum = 0.f;
  #pragma unroll
  for (int s = 0; s < 16; ++s) { v[s] = __expf(v[s] - m); sum += v[s]; }
  #pragma unroll
  for (int off = 32; off; off >>= 1) sum += __shfl_xor(sum, off);
  float inv = 1.f / sum;
  #pragma unroll
  for (int s = 0; s < 8; ++s) { r0[s] = f2bf(v[s] * inv); r1[s] = f2bf(v[8 + s] * inv); }
  *(u16x8*)rp = r0;
  *(u16x8*)(rp + 8) = r1;
}

// ---------------------------------------------------------------------------
// maskcat: Acat[bl][m][k*1024+n] = bf16(chebT[k][m][n] * ST[bbase+bl][m][n])
// all 3 k per thread (ST read once). 8 n per thread.
// ---------------------------------------------------------------------------
__global__ __launch_bounds__(256) void maskcat_kernel(
    const float* __restrict__ chebT, const unsigned short* __restrict__ ST,
    unsigned short* __restrict__ Acat, int bbase) {
  int tg = blockIdx.x * 256 + threadIdx.x;   // 2^20 threads per half
  int n0 = (tg & 127) * 8;
  int m  = (tg >> 7) & 1023;
  int bl = tg >> 17;
  const unsigned short* sp = ST + ((size_t)(bbase + bl) * Nc + m) * Nc + n0;
  u16x8 s = *(const u16x8*)sp;
  float sv[8];
  #pragma unroll
  for (int e = 0; e < 8; ++e) sv[e] = bf2f(s[e]);
  unsigned short* ap = Acat + ((size_t)bl * Nc + m) * KKc + n0;
  #pragma unroll
  for (int k = 0; k < Kc; ++k) {
    const float* cp = chebT + ((size_t)k * Nc + m) * Nc + n0;
    float4 c0 = *(const float4*)cp;
    float4 c1 = *(const float4*)(cp + 4);
    u16x8 o;
    o[0] = f2bf(c0.x * sv[0]);
    o[1] = f2bf(c0.y * sv[1]);
    o[2] = f2bf(c0.z * sv[2]);
    o[3] = f2bf(c0.w * sv[3]);
    o[4] = f2bf(c1.x * sv[4]);
    o[5] = f2bf(c1.y * sv[5]);
    o[6] = f2bf(c1.z * sv[6]);
    o[7] = f2bf(c1.w * sv[7]);
    *(u16x8*)(ap + k * Nc) = o;
  }
}

// ---------------------------------------------------------------------------
// MFMA GEMM (m97 structure): C[m][n] = sum_k A[m][k]*B[n][k], 128x128 tile,
// K-step 32, global_load_lds width-16. MODE 0: bf16 C; MODE 1: fp32 relu C.
// ---------------------------------------------------------------------------
template <int MODE>
__global__ __launch_bounds__(256) void mfma_gemm_bt(
    const unsigned short* __restrict__ A, const unsigned short* __restrict__ B,
    void* __restrict__ Cv, int K, int CN,
    long long Abatch, long long Bbatch, long long Cbatch) {
  __shared__ unsigned short As[128 * 32];
  __shared__ unsigned short Bs[128 * 32];
  int b = blockIdx.z;
  int tid = threadIdx.x;
  int wave = tid >> 6, lane = tid & 63;
  const unsigned short* Ag = A + (size_t)b * Abatch + (size_t)blockIdx.y * 128 * K;
  const unsigned short* Bg = B + (size_t)b * Bbatch + (size_t)blockIdx.x * 128 * K;
  int srow = wave * 32 + (lane >> 2);
  int scol = (lane & 3) * 8;
  const unsigned short* ag0 = Ag + (size_t)srow * K + scol;
  const unsigned short* ag1 = ag0 + (size_t)16 * K;
  const unsigned short* bg0 = Bg + (size_t)srow * K + scol;
  const unsigned short* bg1 = bg0 + (size_t)16 * K;
  unsigned short* as0 = As + (wave * 32) * 32;
  unsigned short* as1 = As + (wave * 32 + 16) * 32;
  unsigned short* bs0 = Bs + (wave * 32) * 32;
  unsigned short* bs1 = Bs + (wave * 32 + 16) * 32;
  int rw = (wave >> 1) * 64, cw = (wave & 1) * 64;
  int frow = lane & 15, fk = (lane >> 4) * 8;
  f32x4 zero = {0.f, 0.f, 0.f, 0.f};
  f32x4 acc[4][4];
  #pragma unroll
  for (int i = 0; i < 4; ++i)
    #pragma unroll
    for (int j = 0; j < 4; ++j) acc[i][j] = zero;

  for (int k0 = 0; k0 < K; k0 += 32) {
    GLL16(ag0, as0); GLL16(ag1, as1);
    GLL16(bg0, bs0); GLL16(bg1, bs1);
    ag0 += 32; ag1 += 32; bg0 += 32; bg1 += 32;
    __syncthreads();
    short8 afr[4], bfr[4];
    #pragma unroll
    for (int i = 0; i < 4; ++i)
      afr[i] = *(const short8*)&As[(rw + i * 16 + frow) * 32 + fk];
    #pragma unroll
    for (int j = 0; j < 4; ++j)
      bfr[j] = *(const short8*)&Bs[(cw + j * 16 + frow) * 32 + fk];
    #pragma unroll
    for (int i = 0; i < 4; ++i)
      #pragma unroll
      for (int j = 0; j < 4; ++j)
        acc[i][j] = mfma16(afr[i], bfr[j], acc[i][j]);
    __syncthreads();
  }
  int q = lane >> 4, cl = lane & 15;
  if (MODE == 0) {
    unsigned short* Cg = (unsigned short*)Cv + (size_t)b * Cbatch
                         + (size_t)blockIdx.y * 128 * CN + (size_t)blockIdx.x * 128;
    #pragma unroll
    for (int i = 0; i < 4; ++i)
      #pragma unroll
      for (int j = 0; j < 4; ++j)
        #pragma unroll
        for (int e = 0; e < 4; ++e)
          Cg[(size_t)(rw + i * 16 + q * 4 + e) * CN + cw + j * 16 + cl] =
              f2bf(acc[i][j][e]);
  } else {
    float* Cg = (float*)Cv + (size_t)b * Cbatch
                + (size_t)blockIdx.y * 128 * CN + (size_t)blockIdx.x * 128;
    #pragma unroll
    for (int i = 0; i < 4; ++i)
      #pragma unroll
      for (int j = 0; j < 4; ++j)
        #pragma unroll
        for (int e = 0; e < 4; ++e)
          Cg[(size_t)(rw + i * 16 + q * 4 + e) * CN + cw + j * 16 + cl] =
              fmaxf(acc[i][j][e], 0.f);
  }
}

// ---------------------------------------------------------------------------
// y2 GEMM: for z=(bl,t): ycat[bl][(o*24+t)][k*1024+n] =
//   sum_f tcat[(k*64+o)][f] * xt2[bbase+bl][n][t][f].  K=64, A-rows padded 256.
// ---------------------------------------------------------------------------
__global__ __launch_bounds__(256) void y2_gemm(
    const unsigned short* __restrict__ tcat, const unsigned short* __restrict__ xt2,
    unsigned short* __restrict__ ycat, int bbase) {
  __shared__ unsigned short As[128 * 32];
  __shared__ unsigned short Bs[128 * 32];
  int z = blockIdx.z;
  int bl = z / 24, t = z - bl * 24;
  int tid = threadIdx.x, wave = tid >> 6, lane = tid & 63;
  const unsigned short* Ag = tcat + (size_t)blockIdx.y * 128 * 64;
  const unsigned short* Bg = xt2 + ((size_t)(bbase + bl) * Nc + (size_t)blockIdx.x * 128) * Cc
                             + (size_t)t * 64;
  int srow = wave * 32 + (lane >> 2);
  int scol = (lane & 3) * 8;
  const unsigned short* ag0 = Ag + (size_t)srow * 64 + scol;
  const unsigned short* ag1 = ag0 + (size_t)16 * 64;
  const unsigned short* bg0 = Bg + (size_t)srow * Cc + scol;
  const unsigned short* bg1 = bg0 + (size_t)16 * Cc;
  unsigned short* as0 = As + (wave * 32) * 32;
  unsigned short* as1 = As + (wave * 32 + 16) * 32;
  unsigned short* bs0 = Bs + (wave * 32) * 32;
  unsigned short* bs1 = Bs + (wave * 32 + 16) * 32;
  int rw = (wave >> 1) * 64, cw = (wave & 1) * 64;
  int frow = lane & 15, fk = (lane >> 4) * 8;
  f32x4 zero = {0.f, 0.f, 0.f, 0.f};
  f32x4 acc[4][4];
  #pragma unroll
  for (int i = 0; i < 4; ++i)
    #pragma unroll
    for (int j = 0; j < 4; ++j) acc[i][j] = zero;

  for (int k0 = 0; k0 < 64; k0 += 32) {
    GLL16(ag0, as0); GLL16(ag1, as1);
    GLL16(bg0, bs0); GLL16(bg1, bs1);
    ag0 += 32; ag1 += 32; bg0 += 32; bg1 += 32;
    __syncthreads();
    short8 afr[4], bfr[4];
    #pragma unroll
    for (int i = 0; i < 4; ++i)
      afr[i] = *(const short8*)&As[(rw + i * 16 + frow) * 32 + fk];
    #pragma unroll
    for (int j = 0; j < 4; ++j)
      bfr[j] = *(const short8*)&Bs[(cw + j * 16 + frow) * 32 + fk];
    #pragma unroll
    for (int i = 0; i < 4; ++i)
      #pragma unroll
      for (int j = 0; j < 4; ++j)
        acc[i][j] = mfma16(afr[i], bfr[j], acc[i][j]);
    __syncthreads();
  }
  int q = lane >> 4, cl = lane & 15;
  unsigned short* yb = ycat + (size_t)bl * Cc * KKc + (size_t)t * KKc;
  #pragma unroll
  for (int i = 0; i < 4; ++i)
    #pragma unroll
    for (int e = 0; e < 4; ++e) {
      int m2 = blockIdx.y * 128 + rw + i * 16 + q * 4 + e;
      if (m2 < 192) {
        int kk = m2 >> 6, o = m2 & 63;
        unsigned short* dst = yb + (size_t)o * 24 * KKc + kk * Nc;
        #pragma unroll
        for (int j = 0; j < 4; ++j)
          dst[blockIdx.x * 128 + cw + j * 16 + cl] = f2bf(acc[i][j][e]);
      }
    }
}

// ---------------------------------------------------------------------------
extern "C" void kernel_launch(void* const* d_in, const int* in_sizes, int n_in,
                              void* d_out, int out_size, void* d_ws, size_t ws_size,
                              hipStream_t stream) {
  const float* x     = (const float*)d_in[0];
  const float* W1    = (const float*)d_in[1];
  const float* W2    = (const float*)d_in[2];
  const float* W3    = (const float*)d_in[3];
  const float* bs    = (const float*)d_in[4];
  const float* Vs    = (const float*)d_in[5];
  const float* cheb  = (const float*)d_in[6];
  const float* Theta = (const float*)d_in[7];
  float* out = (float*)d_out;

  // Workspace layout (bytes). ycat_h region doubles as front-phase temps
  // (lhs/rhs/sigT/Vsbf all dead before y2 runs). Total ~222.3 MB.
  char* w = (char*)d_ws;
  unsigned short* ycat = (unsigned short*)w;                    // 75,497,472 B (8*1536*3072*2)
  float* lhs = (float*)w;                                       // 1,572,864
  float* rhs = (float*)(w + 1572864);                           // 1,572,864
  unsigned short* sigT = (unsigned short*)(w + 3145728);        // 33,554,432
  unsigned short* Vsbf = (unsigned short*)(w + 36700160);       // 2,097,152 (ends 38.8MB < 75.5MB)
  unsigned short* Acat = (unsigned short*)(w + 75497472);       // 50,331,648 (8*1024*3072*2)
  unsigned short* ST   = (unsigned short*)(w + 125829120);      // 33,554,432
  float* chebT         = (float*)(w + 159383552);               // 12,582,912
  unsigned short* xt2  = (unsigned short*)(w + 171966464);      // 50,331,648
  unsigned short* tcat = (unsigned short*)(w + 222298112);      // 32,768  -> end 222,330,880

  prep_kernel<<<Bc * Nc, 64, 0, stream>>>(x, W1, W2, W3, lhs, rhs);
  prodsigT_kernel<<<dim3(Nc / 64, Nc / 64, Bc), 256, 0, stream>>>(lhs, rhs, bs, sigT);
  cvt_vs_kernel<<<Nc * Nc / 1024, 256, 0, stream>>>(Vs, Vsbf);
  // ST[b][j][i] = sum_kk sigT[b][j][kk] * Vs[i][kk]
  mfma_gemm_bt<0><<<dim3(Nc / 128, Nc / 128, Bc), 256, 0, stream>>>(
      sigT, Vsbf, ST, Nc, Nc, (long long)Nc * Nc, 0LL, (long long)Nc * Nc);
  softmax_rows_kernel<<<Bc * Nc / 4, 256, 0, stream>>>(ST);
  chebT_kernel<<<dim3(Nc / 64, Nc / 64, Kc), 256, 0, stream>>>(cheb, chebT);
  xt2_kernel<<<Bc * Nc / 4, 256, 0, stream>>>(x, xt2);
  tcat_kernel<<<64, 256, 0, stream>>>(Theta, tcat);

  for (int half = 0; half < 2; ++half) {
    int bbase = half * 8;
    maskcat_kernel<<<4096, 256, 0, stream>>>(chebT, ST, Acat, bbase);
    y2_gemm<<<dim3(Nc / 128, 2, 8 * 24), 256, 0, stream>>>(tcat, xt2, ycat, bbase);
    // out[b][m][o*24+t] = relu( sum_{kk<3072} Acat[bl][m][kk] * ycat[bl][c''][kk] )
    mfma_gemm_bt<1><<<dim3(Cc / 128, Nc / 128, 8), 256, 0, stream>>>(
        Acat, ycat, out + (size_t)bbase * Nc * Cc, KKc, Cc,
        (long long)Nc * KKc, (long long)Cc * KKc, (long long)Nc * Cc);
  }
}

// Round 4
// 566.527 us; speedup vs baseline: 5.7058x; 1.1647x over previous
//
#include <hip/hip_runtime.h>
#include <math.h>

// Problem constants: B=16, N=1024, F=64, T=24, K=3, FO=64
#define Bc 16
#define Nc 1024
#define Fc 64
#define Tc 24
#define Kc 3
#define FOc 64
#define Cc (Fc*Tc)      // 1536
#define KKc (Kc*Nc)     // 3072 = fused reduction length

typedef __attribute__((ext_vector_type(8))) short short8;   // 8 bf16 (4 VGPRs)
typedef __attribute__((ext_vector_type(8))) unsigned short u16x8;
typedef __attribute__((ext_vector_type(4))) float f32x4;

__device__ __forceinline__ unsigned short f2bf(float f) {
  unsigned u = __float_as_uint(f);
  u += 0x7fff + ((u >> 16) & 1);   // round-to-nearest-even
  return (unsigned short)(u >> 16);
}
__device__ __forceinline__ float bf2f(unsigned short h) {
  return __uint_as_float((unsigned)h << 16);
}

#define GLL16(g, l) __builtin_amdgcn_global_load_lds( \
    (const __attribute__((address_space(1))) void*)(g), \
    (__attribute__((address_space(3))) void*)(l), 16, 0, 0)

__device__ __forceinline__ f32x4 mfma16(short8 a, short8 b, f32x4 c) {
  return __builtin_amdgcn_mfma_f32_16x16x32_bf16(a, b, c, 0, 0, 0);
}

// ---------------------------------------------------------------------------
// GEMM core: 128x128 tile, BK=64, XOR-swizzled LDS (conflict-free ds_read).
// LDS row = 64 elems = 128 B. Physical 16B-chunk p of row r holds logical
// chunk p^(r&7). Staging lane l (within a 1KB call covering 8 rows):
// row r=l>>3, physical chunk l&7 -> load logical ((l&7)^(l>>3)).
// Fragment read (row R=rw+i*16+frow, logical chunk q+4h): p=(q+4h)^(frow&7)
// (R&7 == frow&7 since rw,i*16 are multiples of 8).
// ---------------------------------------------------------------------------
__device__ __forceinline__ void gemm_core(
    const unsigned short* __restrict__ Ag, const unsigned short* __restrict__ Bg,
    int lda, int ldb, int K,
    unsigned short* As, unsigned short* Bs,
    int wave, int lane, f32x4 acc[4][4]) {
  int sr = lane >> 3;                    // row within a 1KB staging call
  int sc = ((lane & 7) ^ sr) * 8;        // swizzled source column (elems)
  const unsigned short* a0 = Ag + (size_t)(wave * 32 + sr) * lda + sc;
  const unsigned short* b0 = Bg + (size_t)(wave * 32 + sr) * ldb + sc;
  unsigned short* asw = As + (wave * 32) * 64;
  unsigned short* bsw = Bs + (wave * 32) * 64;
  int rw = (wave >> 1) * 64, cw = (wave & 1) * 64;
  int frow = lane & 15;
  int q = lane >> 4;
  int p0 = (q ^ (frow & 7)) * 8;         // half 0 chunk offset (elems)
  int p1 = ((q | 4) ^ (frow & 7)) * 8;   // half 1
  for (int k0 = 0; k0 < K; k0 += 64) {
    #pragma unroll
    for (int c = 0; c < 4; ++c) {
      GLL16(a0 + (size_t)(c * 8) * lda + k0, asw + (c * 8) * 64);
      GLL16(b0 + (size_t)(c * 8) * ldb + k0, bsw + (c * 8) * 64);
    }
    __syncthreads();
    #pragma unroll
    for (int h = 0; h < 2; ++h) {
      int p = h ? p1 : p0;
      short8 afr[4], bfr[4];
      #pragma unroll
      for (int i = 0; i < 4; ++i)
        afr[i] = *(const short8*)&As[(rw + i * 16 + frow) * 64 + p];
      #pragma unroll
      for (int j = 0; j < 4; ++j)
        bfr[j] = *(const short8*)&Bs[(cw + j * 16 + frow) * 64 + p];
      #pragma unroll
      for (int i = 0; i < 4; ++i)
        #pragma unroll
        for (int j = 0; j < 4; ++j)
          acc[i][j] = mfma16(afr[i], bfr[j], acc[i][j]);
    }
    __syncthreads();
  }
}

// ---------------------------------------------------------------------------
// xprep: single pass over x producing xt2[b][n][t][f] (bf16) AND
// lhs/rhs (fp32) for the attention front-end. One wave per (b,n) row.
// ---------------------------------------------------------------------------
__global__ __launch_bounds__(256) void xprep_kernel(
    const float* __restrict__ x, const float* __restrict__ W1,
    const float* __restrict__ W2, const float* __restrict__ W3,
    unsigned short* __restrict__ xt2, float* __restrict__ lhs,
    float* __restrict__ rhs) {
  __shared__ float ld[4 * 1560];   // per wave: [t][f] stride 65 (pad)
  __shared__ float af[4 * 64];
  int w = threadIdx.x >> 6, lane = threadIdx.x & 63;
  size_t n = (size_t)blockIdx.x * 4 + w;
  const float* xp = x + n * Cc;
  float* lw = ld + w * 1560;
  // load x row (coalesced) -> transposed fp32 LDS [t][f]
  #pragma unroll
  for (int j = 0; j < 24; ++j) {
    int i = j * 64 + lane;
    int f = i / 24, t = i - f * 24;
    lw[t * 65 + f] = xp[i];
  }
  __syncthreads();
  // a_f = sum_t x[f,t]*W1[t]  (lane = f)
  float a = 0.f;
  #pragma unroll
  for (int t = 0; t < Tc; ++t) a += lw[t * 65 + lane] * W1[t];
  af[w * 64 + lane] = a;
  // xt2 store: [t][f] contiguous bf16
  #pragma unroll
  for (int j = 0; j < 24; ++j)
    xt2[n * Cc + j * 64 + lane] = f2bf(lw[j * 65 + lane]);
  __syncthreads();
  if (lane < Tc) {
    float l = 0.f, r = 0.f;
    #pragma unroll 8
    for (int f = 0; f < Fc; ++f) {
      l += af[w * 64 + f] * W2[f * Tc + lane];
      r += W3[f] * lw[lane * 65 + f];
    }
    lhs[n * Tc + lane] = l;
    rhs[n * Tc + lane] = r;
  }
}

// ---------------------------------------------------------------------------
// Phase 2: sigT[b][p][q] = bf16(sigmoid(dot(lhs[b][q],rhs[b][p]) + bs[q][p]))
// ---------------------------------------------------------------------------
__global__ __launch_bounds__(256) void prodsigT_kernel(
    const float* __restrict__ lhs, const float* __restrict__ rhs,
    const float* __restrict__ bs, unsigned short* __restrict__ sigT) {
  int b = blockIdx.z;
  int p0 = blockIdx.y * 64, q0 = blockIdx.x * 64;
  __shared__ float Ls[64 * 25], Rs[64 * 25], Bt[64 * 65];
  int tid = threadIdx.x;
  const float* lp = lhs + ((size_t)b * Nc + q0) * Tc;
  const float* rp = rhs + ((size_t)b * Nc + p0) * Tc;
  for (int i = tid; i < 64 * Tc; i += 256) {
    Ls[(i / Tc) * 25 + i % Tc] = lp[i];
    Rs[(i / Tc) * 25 + i % Tc] = rp[i];
  }
  for (int i = tid; i < 1024; i += 256) {
    int qr = i >> 4, pc = (i & 15) * 4;
    *(float4*)&Bt[qr * 65 + pc] = *(const float4*)&bs[(size_t)(q0 + qr) * Nc + p0 + pc];
  }
  __syncthreads();
  int tx = tid % 16, ty = tid / 16;
  float acc[4][4] = {};
  for (int t = 0; t < Tc; ++t) {
    float rv[4], lv[4];
    #pragma unroll
    for (int i = 0; i < 4; ++i) rv[i] = Rs[(ty * 4 + i) * 25 + t];
    #pragma unroll
    for (int j = 0; j < 4; ++j) lv[j] = Ls[(tx * 4 + j) * 25 + t];
    #pragma unroll
    for (int i = 0; i < 4; ++i)
      #pragma unroll
      for (int j = 0; j < 4; ++j) acc[i][j] += rv[i] * lv[j];
  }
  #pragma unroll
  for (int i = 0; i < 4; ++i) {
    int p = p0 + ty * 4 + i;
    ushort4 o;
    float v0 = acc[i][0] + Bt[(tx * 4 + 0) * 65 + ty * 4 + i];
    float v1 = acc[i][1] + Bt[(tx * 4 + 1) * 65 + ty * 4 + i];
    float v2 = acc[i][2] + Bt[(tx * 4 + 2) * 65 + ty * 4 + i];
    float v3 = acc[i][3] + Bt[(tx * 4 + 3) * 65 + ty * 4 + i];
    o.x = f2bf(1.f / (1.f + __expf(-v0)));
    o.y = f2bf(1.f / (1.f + __expf(-v1)));
    o.z = f2bf(1.f / (1.f + __expf(-v2)));
    o.w = f2bf(1.f / (1.f + __expf(-v3)));
    *(ushort4*)&sigT[((size_t)b * Nc + p) * Nc + q0 + tx * 4] = o;
  }
}

// ---------------------------------------------------------------------------
__global__ __launch_bounds__(256) void cvt_vs_kernel(
    const float* __restrict__ Vs, unsigned short* __restrict__ Vsbf) {
  int i = (blockIdx.x * 256 + threadIdx.x) * 4;
  float4 v = *(const float4*)&Vs[i];
  ushort4 o;
  o.x = f2bf(v.x); o.y = f2bf(v.y); o.z = f2bf(v.z); o.w = f2bf(v.w);
  *(ushort4*)&Vsbf[i] = o;
}

// ---------------------------------------------------------------------------
// chebT[k][m][n] = cheb[k][n][m] (fp32 transpose)
// ---------------------------------------------------------------------------
__global__ __launch_bounds__(256) void chebT_kernel(
    const float* __restrict__ cheb, float* __restrict__ chebT) {
  int k = blockIdx.z;
  int n0 = blockIdx.y * 64, m0 = blockIdx.x * 64;
  __shared__ float t[64 * 65];
  const float* src = cheb + (size_t)k * Nc * Nc;
  float* dst = chebT + (size_t)k * Nc * Nc;
  int tid = threadIdx.x;
  #pragma unroll
  for (int s = 0; s < 4; ++s) {
    int nr = (tid >> 4) + s * 16, mc = (tid & 15) * 4;
    float4 v = *(const float4*)&src[(size_t)(n0 + nr) * Nc + m0 + mc];
    t[(mc + 0) * 65 + nr] = v.x;
    t[(mc + 1) * 65 + nr] = v.y;
    t[(mc + 2) * 65 + nr] = v.z;
    t[(mc + 3) * 65 + nr] = v.w;
  }
  __syncthreads();
  #pragma unroll
  for (int s = 0; s < 4; ++s) {
    int mr = (tid >> 4) + s * 16, nc = (tid & 15) * 4;
    float4 v = {t[mr * 65 + nc], t[mr * 65 + nc + 1], t[mr * 65 + nc + 2], t[mr * 65 + nc + 3]};
    *(float4*)&dst[(size_t)(m0 + mr) * Nc + n0 + nc] = v;
  }
}

// ---------------------------------------------------------------------------
// tcat[(k*64+o)][f] = bf16(Theta[k][f][o]); 256 rows alloc, rows>=192 zeroed
// ---------------------------------------------------------------------------
__global__ __launch_bounds__(256) void tcat_kernel(
    const float* __restrict__ Theta, unsigned short* __restrict__ tcat) {
  int i = blockIdx.x * 256 + threadIdx.x;   // 0..16383
  int m2 = i >> 6, f = i & 63;
  int k = m2 >> 6, o = m2 & 63;
  tcat[i] = (m2 < 192) ? f2bf(Theta[((size_t)k * Fc + f) * FOc + o])
                       : (unsigned short)0;
}

// ---------------------------------------------------------------------------
// masksoft: per (bl,m) row of ST: softmax over n (fp32), then
// Acat[bl][m][k*1024+n] = bf16(chebT[k][m][n] * softmax_n)
// ---------------------------------------------------------------------------
__global__ __launch_bounds__(256) void masksoft_kernel(
    const float* __restrict__ chebT, const unsigned short* __restrict__ ST,
    unsigned short* __restrict__ Acat, int bbase) {
  int m  = blockIdx.x & (Nc - 1);
  int bl = blockIdx.x >> 10;
  int tid = threadIdx.x;
  const unsigned short* sp = ST + ((size_t)(bbase + bl) * Nc + m) * Nc;
  ushort4 s4 = *(const ushort4*)(sp + tid * 4);
  float v0 = bf2f(s4.x), v1 = bf2f(s4.y), v2 = bf2f(s4.z), v3 = bf2f(s4.w);
  __shared__ float redm[4], reds[4];
  int wave = tid >> 6, lane = tid & 63;
  float mx = fmaxf(fmaxf(v0, v1), fmaxf(v2, v3));
  #pragma unroll
  for (int off = 32; off; off >>= 1) mx = fmaxf(mx, __shfl_xor(mx, off));
  if (lane == 0) redm[wave] = mx;
  __syncthreads();
  mx = fmaxf(fmaxf(redm[0], redm[1]), fmaxf(redm[2], redm[3]));
  float e0 = __expf(v0 - mx), e1 = __expf(v1 - mx);
  float e2 = __expf(v2 - mx), e3 = __expf(v3 - mx);
  float sm = e0 + e1 + e2 + e3;
  #pragma unroll
  for (int off = 32; off; off >>= 1) sm += __shfl_xor(sm, off);
  if (lane == 0) reds[wave] = sm;
  __syncthreads();
  float inv = 1.f / (reds[0] + reds[1] + reds[2] + reds[3]);
  e0 *= inv; e1 *= inv; e2 *= inv; e3 *= inv;
  unsigned short* ap = Acat + ((size_t)bl * Nc + m) * KKc + tid * 4;
  #pragma unroll
  for (int k = 0; k < Kc; ++k) {
    float4 c = *(const float4*)&chebT[((size_t)k * Nc + m) * Nc + tid * 4];
    ushort4 o;
    o.x = f2bf(c.x * e0); o.y = f2bf(c.y * e1);
    o.z = f2bf(c.z * e2); o.w = f2bf(c.w * e3);
    *(ushort4*)(ap + k * Nc) = o;
  }
}

// ---------------------------------------------------------------------------
// MFMA GEMM: C[m][n] = sum_k A[m][k]*B[n][k]. MODE 0: bf16 C; 1: fp32 relu C.
// ---------------------------------------------------------------------------
template <int MODE>
__global__ __launch_bounds__(256) void mfma_gemm_bt(
    const unsigned short* __restrict__ A, const unsigned short* __restrict__ B,
    void* __restrict__ Cv, int K, int CN,
    long long Abatch, long long Bbatch, long long Cbatch) {
  __shared__ unsigned short As[128 * 64];
  __shared__ unsigned short Bs[128 * 64];
  int b = blockIdx.z;
  int tid = threadIdx.x, wave = tid >> 6, lane = tid & 63;
  const unsigned short* Ag = A + (size_t)b * Abatch + (size_t)blockIdx.y * 128 * K;
  const unsigned short* Bg = B + (size_t)b * Bbatch + (size_t)blockIdx.x * 128 * K;
  f32x4 zero = {0.f, 0.f, 0.f, 0.f};
  f32x4 acc[4][4];
  #pragma unroll
  for (int i = 0; i < 4; ++i)
    #pragma unroll
    for (int j = 0; j < 4; ++j) acc[i][j] = zero;
  gemm_core(Ag, Bg, K, K, K, As, Bs, wave, lane, acc);
  int rw = (wave >> 1) * 64, cw = (wave & 1) * 64;
  int q = lane >> 4, cl = lane & 15;
  if (MODE == 0) {
    unsigned short* Cg = (unsigned short*)Cv + (size_t)b * Cbatch
                         + (size_t)blockIdx.y * 128 * CN + (size_t)blockIdx.x * 128;
    #pragma unroll
    for (int i = 0; i < 4; ++i)
      #pragma unroll
      for (int j = 0; j < 4; ++j)
        #pragma unroll
        for (int e = 0; e < 4; ++e)
          Cg[(size_t)(rw + i * 16 + q * 4 + e) * CN + cw + j * 16 + cl] =
              f2bf(acc[i][j][e]);
  } else {
    float* Cg = (float*)Cv + (size_t)b * Cbatch
                + (size_t)blockIdx.y * 128 * CN + (size_t)blockIdx.x * 128;
    #pragma unroll
    for (int i = 0; i < 4; ++i)
      #pragma unroll
      for (int j = 0; j < 4; ++j)
        #pragma unroll
        for (int e = 0; e < 4; ++e)
          Cg[(size_t)(rw + i * 16 + q * 4 + e) * CN + cw + j * 16 + cl] =
              fmaxf(acc[i][j][e], 0.f);
  }
}

// ---------------------------------------------------------------------------
// y2 GEMM: for z=(bl,t): ycat[bl][(o*24+t)][k*1024+n] =
//   sum_f tcat[(k*64+o)][f] * xt2[bbase+bl][n][t][f].  K=64.
// ---------------------------------------------------------------------------
__global__ __launch_bounds__(256) void y2_gemm(
    const unsigned short* __restrict__ tcat, const unsigned short* __restrict__ xt2,
    unsigned short* __restrict__ ycat, int bbase) {
  __shared__ unsigned short As[128 * 64];
  __shared__ unsigned short Bs[128 * 64];
  int z = blockIdx.z;
  int bl = z / 24, t = z - bl * 24;
  int tid = threadIdx.x, wave = tid >> 6, lane = tid & 63;
  const unsigned short* Ag = tcat + (size_t)blockIdx.y * 128 * 64;
  const unsigned short* Bg = xt2 + ((size_t)(bbase + bl) * Nc + (size_t)blockIdx.x * 128) * Cc
                             + (size_t)t * 64;
  f32x4 zero = {0.f, 0.f, 0.f, 0.f};
  f32x4 acc[4][4];
  #pragma unroll
  for (int i = 0; i < 4; ++i)
    #pragma unroll
    for (int j = 0; j < 4; ++j) acc[i][j] = zero;
  gemm_core(Ag, Bg, 64, Cc, 64, As, Bs, wave, lane, acc);
  int rw = (wave >> 1) * 64, cw = (wave & 1) * 64;
  int q = lane >> 4, cl = lane & 15;
  unsigned short* yb = ycat + (size_t)bl * Cc * KKc + (size_t)t * KKc;
  #pragma unroll
  for (int i = 0; i < 4; ++i)
    #pragma unroll
    for (int e = 0; e < 4; ++e) {
      int m2 = blockIdx.y * 128 + rw + i * 16 + q * 4 + e;
      if (m2 < 192) {
        int kk = m2 >> 6, o = m2 & 63;
        unsigned short* dst = yb + (size_t)o * 24 * KKc + kk * Nc;
        #pragma unroll
        for (int j = 0; j < 4; ++j)
          dst[blockIdx.x * 128 + cw + j * 16 + cl] = f2bf(acc[i][j][e]);
      }
    }
}

// ---------------------------------------------------------------------------
extern "C" void kernel_launch(void* const* d_in, const int* in_sizes, int n_in,
                              void* d_out, int out_size, void* d_ws, size_t ws_size,
                              hipStream_t stream) {
  const float* x     = (const float*)d_in[0];
  const float* W1    = (const float*)d_in[1];
  const float* W2    = (const float*)d_in[2];
  const float* W3    = (const float*)d_in[3];
  const float* bs    = (const float*)d_in[4];
  const float* Vs    = (const float*)d_in[5];
  const float* cheb  = (const float*)d_in[6];
  const float* Theta = (const float*)d_in[7];
  float* out = (float*)d_out;

  // Workspace: ycat region doubles as front-phase temps (lhs/rhs/sigT/Vsbf
  // all dead before y2 writes ycat). Total ~222.3 MB.
  char* w = (char*)d_ws;
  unsigned short* ycat = (unsigned short*)w;                    // 75,497,472 B
  float* lhs = (float*)w;                                       // 1,572,864
  float* rhs = (float*)(w + 1572864);                           // 1,572,864
  unsigned short* sigT = (unsigned short*)(w + 3145728);        // 33,554,432
  unsigned short* Vsbf = (unsigned short*)(w + 36700160);       // 2,097,152
  unsigned short* Acat = (unsigned short*)(w + 75497472);       // 50,331,648
  unsigned short* ST   = (unsigned short*)(w + 125829120);      // 33,554,432
  float* chebT         = (float*)(w + 159383552);               // 12,582,912
  unsigned short* xt2  = (unsigned short*)(w + 171966464);      // 50,331,648
  unsigned short* tcat = (unsigned short*)(w + 222298112);      // 32,768

  xprep_kernel<<<Bc * Nc / 4, 256, 0, stream>>>(x, W1, W2, W3, xt2, lhs, rhs);
  prodsigT_kernel<<<dim3(Nc / 64, Nc / 64, Bc), 256, 0, stream>>>(lhs, rhs, bs, sigT);
  cvt_vs_kernel<<<Nc * Nc / 1024, 256, 0, stream>>>(Vs, Vsbf);
  // ST[b][j][i] = sum_kk sigT[b][j][kk] * Vs[i][kk]
  mfma_gemm_bt<0><<<dim3(Nc / 128, Nc / 128, Bc), 256, 0, stream>>>(
      sigT, Vsbf, ST, Nc, Nc, (long long)Nc * Nc, 0LL, (long long)Nc * Nc);
  chebT_kernel<<<dim3(Nc / 64, Nc / 64, Kc), 256, 0, stream>>>(cheb, chebT);
  tcat_kernel<<<64, 256, 0, stream>>>(Theta, tcat);

  for (int half = 0; half < 2; ++half) {
    int bbase = half * 8;
    masksoft_kernel<<<8 * Nc, 256, 0, stream>>>(chebT, ST, Acat, bbase);
    y2_gemm<<<dim3(Nc / 128, 2, 8 * 24), 256, 0, stream>>>(tcat, xt2, ycat, bbase);
    // out[b][m][o*24+t] = relu( sum_{kk<3072} Acat[bl][m][kk] * ycat[bl][c''][kk] )
    mfma_gemm_bt<1><<<dim3(Cc / 128, Nc / 128, 8), 256, 0, stream>>>(
        Acat, ycat, out + (size_t)bbase * Nc * Cc, KKc, Cc,
        (long long)Nc * KKc, (long long)Cc * KKc, (long long)Nc * Cc);
  }
}

// Round 5
// 557.071 us; speedup vs baseline: 5.8027x; 1.0170x over previous
//
#include <hip/hip_runtime.h>
#include <math.h>

// Problem constants: B=16, N=1024, F=64, T=24, K=3, FO=64
#define Bc 16
#define Nc 1024
#define Fc 64
#define Tc 24
#define Kc 3
#define FOc 64
#define Cc (Fc*Tc)      // 1536
#define KKc (Kc*Nc)     // 3072 = fused reduction length

typedef __attribute__((ext_vector_type(8))) short short8;   // 8 bf16 (4 VGPRs)
typedef __attribute__((ext_vector_type(8))) unsigned short u16x8;
typedef __attribute__((ext_vector_type(4))) float f32x4;

__device__ __forceinline__ unsigned short f2bf(float f) {
  unsigned u = __float_as_uint(f);
  u += 0x7fff + ((u >> 16) & 1);   // round-to-nearest-even
  return (unsigned short)(u >> 16);
}
__device__ __forceinline__ float bf2f(unsigned short h) {
  return __uint_as_float((unsigned)h << 16);
}

#define GLL16(g, l) __builtin_amdgcn_global_load_lds( \
    (const __attribute__((address_space(1))) void*)(g), \
    (__attribute__((address_space(3))) void*)(l), 16, 0, 0)

__device__ __forceinline__ f32x4 mfma16(short8 a, short8 b, f32x4 c) {
  return __builtin_amdgcn_mfma_f32_16x16x32_bf16(a, b, c, 0, 0, 0);
}

// ---------------------------------------------------------------------------
// GEMM core: 128x128 tile, BK=64, XOR-swizzled LDS (conflict-free, R4-verified).
// ---------------------------------------------------------------------------
__device__ __forceinline__ void gemm_core(
    const unsigned short* __restrict__ Ag, const unsigned short* __restrict__ Bg,
    int lda, int ldb, int K,
    unsigned short* As, unsigned short* Bs,
    int wave, int lane, f32x4 acc[4][4]) {
  int sr = lane >> 3;                    // row within a 1KB staging call
  int sc = ((lane & 7) ^ sr) * 8;        // swizzled source column (elems)
  const unsigned short* a0 = Ag + (size_t)(wave * 32 + sr) * lda + sc;
  const unsigned short* b0 = Bg + (size_t)(wave * 32 + sr) * ldb + sc;
  unsigned short* asw = As + (wave * 32) * 64;
  unsigned short* bsw = Bs + (wave * 32) * 64;
  int rw = (wave >> 1) * 64, cw = (wave & 1) * 64;
  int frow = lane & 15;
  int q = lane >> 4;
  int p0 = (q ^ (frow & 7)) * 8;         // half 0 chunk offset (elems)
  int p1 = ((q | 4) ^ (frow & 7)) * 8;   // half 1
  for (int k0 = 0; k0 < K; k0 += 64) {
    #pragma unroll
    for (int c = 0; c < 4; ++c) {
      GLL16(a0 + (size_t)(c * 8) * lda + k0, asw + (c * 8) * 64);
      GLL16(b0 + (size_t)(c * 8) * ldb + k0, bsw + (c * 8) * 64);
    }
    __syncthreads();
    #pragma unroll
    for (int h = 0; h < 2; ++h) {
      int p = h ? p1 : p0;
      short8 afr[4], bfr[4];
      #pragma unroll
      for (int i = 0; i < 4; ++i)
        afr[i] = *(const short8*)&As[(rw + i * 16 + frow) * 64 + p];
      #pragma unroll
      for (int j = 0; j < 4; ++j)
        bfr[j] = *(const short8*)&Bs[(cw + j * 16 + frow) * 64 + p];
      #pragma unroll
      for (int i = 0; i < 4; ++i)
        #pragma unroll
        for (int j = 0; j < 4; ++j)
          acc[i][j] = mfma16(afr[i], bfr[j], acc[i][j]);
    }
    __syncthreads();
  }
}

// ---------------------------------------------------------------------------
// xprep: single pass over x producing xt2[b][n][t][f] (bf16) AND
// lhsb/rhsb (bf16, K-padded to 64 with zeros) for the MFMA attention GEMM.
// ---------------------------------------------------------------------------
__global__ __launch_bounds__(256) void xprep_kernel(
    const float* __restrict__ x, const float* __restrict__ W1,
    const float* __restrict__ W2, const float* __restrict__ W3,
    unsigned short* __restrict__ xt2, unsigned short* __restrict__ lhsb,
    unsigned short* __restrict__ rhsb) {
  __shared__ float ld[4 * 1560];   // per wave: [t][f] stride 65 (pad)
  __shared__ float af[4 * 64];
  int w = threadIdx.x >> 6, lane = threadIdx.x & 63;
  size_t n = (size_t)blockIdx.x * 4 + w;
  const float* xp = x + n * Cc;
  float* lw = ld + w * 1560;
  #pragma unroll
  for (int j = 0; j < 24; ++j) {
    int i = j * 64 + lane;
    int f = i / 24, t = i - f * 24;
    lw[t * 65 + f] = xp[i];
  }
  __syncthreads();
  float a = 0.f;
  #pragma unroll
  for (int t = 0; t < Tc; ++t) a += lw[t * 65 + lane] * W1[t];
  af[w * 64 + lane] = a;
  #pragma unroll
  for (int j = 0; j < 24; ++j)
    xt2[n * Cc + j * 64 + lane] = f2bf(lw[j * 65 + lane]);
  __syncthreads();
  float l = 0.f, r = 0.f;
  if (lane < Tc) {
    #pragma unroll 8
    for (int f = 0; f < Fc; ++f) {
      l += af[w * 64 + f] * W2[f * Tc + lane];
      r += W3[f] * lw[lane * 65 + f];
    }
  }
  lhsb[n * 64 + lane] = (lane < Tc) ? f2bf(l) : (unsigned short)0;
  rhsb[n * 64 + lane] = (lane < Tc) ? f2bf(r) : (unsigned short)0;
}

// ---------------------------------------------------------------------------
// misc: Vs->bf16 (blocks 0..1023), tcat (1024..1087), bsT transpose (1088..1343)
// ---------------------------------------------------------------------------
__global__ __launch_bounds__(256) void misc_kernel(
    const float* __restrict__ Vs, const float* __restrict__ Theta,
    const float* __restrict__ bs, unsigned short* __restrict__ Vsbf,
    unsigned short* __restrict__ tcat, float* __restrict__ bsT) {
  __shared__ float t[64 * 65];
  int bid = blockIdx.x, tid = threadIdx.x;
  if (bid < 1024) {
    int i = (bid * 256 + tid) * 4;
    float4 v = *(const float4*)&Vs[i];
    ushort4 o;
    o.x = f2bf(v.x); o.y = f2bf(v.y); o.z = f2bf(v.z); o.w = f2bf(v.w);
    *(ushort4*)&Vsbf[i] = o;
  } else if (bid < 1088) {
    int i = (bid - 1024) * 256 + tid;   // 0..16383
    int m2 = i >> 6, f = i & 63;
    int k = m2 >> 6, o = m2 & 63;
    tcat[i] = (m2 < 192) ? f2bf(Theta[((size_t)k * Fc + f) * FOc + o])
                         : (unsigned short)0;
  } else {
    int id = bid - 1088;                 // 0..255: bsT[p][q] = bs[q][p]
    int p0 = (id >> 4) * 64, q0 = (id & 15) * 64;
    #pragma unroll
    for (int s = 0; s < 4; ++s) {
      int qr = (tid >> 4) + s * 16, pc = (tid & 15) * 4;
      float4 v = *(const float4*)&bs[(size_t)(q0 + qr) * Nc + p0 + pc];
      t[(pc + 0) * 65 + qr] = v.x;
      t[(pc + 1) * 65 + qr] = v.y;
      t[(pc + 2) * 65 + qr] = v.z;
      t[(pc + 3) * 65 + qr] = v.w;
    }
    __syncthreads();
    #pragma unroll
    for (int s = 0; s < 4; ++s) {
      int pr = (tid >> 4) + s * 16, qc = (tid & 15) * 4;
      float4 v = {t[pr * 65 + qc], t[pr * 65 + qc + 1],
                  t[pr * 65 + qc + 2], t[pr * 65 + qc + 3]};
      *(float4*)&bsT[(size_t)(p0 + pr) * Nc + q0 + qc] = v;
    }
  }
}

// ---------------------------------------------------------------------------
// chebT[k][m][n] = cheb[k][n][m] (fp32 transpose)
// ---------------------------------------------------------------------------
__global__ __launch_bounds__(256) void chebT_kernel(
    const float* __restrict__ cheb, float* __restrict__ chebT) {
  int k = blockIdx.z;
  int n0 = blockIdx.y * 64, m0 = blockIdx.x * 64;
  __shared__ float t[64 * 65];
  const float* src = cheb + (size_t)k * Nc * Nc;
  float* dst = chebT + (size_t)k * Nc * Nc;
  int tid = threadIdx.x;
  #pragma unroll
  for (int s = 0; s < 4; ++s) {
    int nr = (tid >> 4) + s * 16, mc = (tid & 15) * 4;
    float4 v = *(const float4*)&src[(size_t)(n0 + nr) * Nc + m0 + mc];
    t[(mc + 0) * 65 + nr] = v.x;
    t[(mc + 1) * 65 + nr] = v.y;
    t[(mc + 2) * 65 + nr] = v.z;
    t[(mc + 3) * 65 + nr] = v.w;
  }
  __syncthreads();
  #pragma unroll
  for (int s = 0; s < 4; ++s) {
    int mr = (tid >> 4) + s * 16, nc = (tid & 15) * 4;
    float4 v = {t[mr * 65 + nc], t[mr * 65 + nc + 1], t[mr * 65 + nc + 2], t[mr * 65 + nc + 3]};
    *(float4*)&dst[(size_t)(m0 + mr) * Nc + n0 + nc] = v;
  }
}

// ---------------------------------------------------------------------------
// masksoft: per (bl,m) row of ST: softmax over n (fp32), then
// Acat[bl][m][k*1024+n] = bf16(chebT[k][m][n] * softmax_n)
// ---------------------------------------------------------------------------
__global__ __launch_bounds__(256) void masksoft_kernel(
    const float* __restrict__ chebT, const unsigned short* __restrict__ ST,
    unsigned short* __restrict__ Acat, int bbase) {
  int m  = blockIdx.x & (Nc - 1);
  int bl = blockIdx.x >> 10;
  int tid = threadIdx.x;
  const unsigned short* sp = ST + ((size_t)(bbase + bl) * Nc + m) * Nc;
  ushort4 s4 = *(const ushort4*)(sp + tid * 4);
  float v0 = bf2f(s4.x), v1 = bf2f(s4.y), v2 = bf2f(s4.z), v3 = bf2f(s4.w);
  __shared__ float redm[4], reds[4];
  int wave = tid >> 6, lane = tid & 63;
  float mx = fmaxf(fmaxf(v0, v1), fmaxf(v2, v3));
  #pragma unroll
  for (int off = 32; off; off >>= 1) mx = fmaxf(mx, __shfl_xor(mx, off));
  if (lane == 0) redm[wave] = mx;
  __syncthreads();
  mx = fmaxf(fmaxf(redm[0], redm[1]), fmaxf(redm[2], redm[3]));
  float e0 = __expf(v0 - mx), e1 = __expf(v1 - mx);
  float e2 = __expf(v2 - mx), e3 = __expf(v3 - mx);
  float sm = e0 + e1 + e2 + e3;
  #pragma unroll
  for (int off = 32; off; off >>= 1) sm += __shfl_xor(sm, off);
  if (lane == 0) reds[wave] = sm;
  __syncthreads();
  float inv = 1.f / (reds[0] + reds[1] + reds[2] + reds[3]);
  e0 *= inv; e1 *= inv; e2 *= inv; e3 *= inv;
  unsigned short* ap = Acat + ((size_t)bl * Nc + m) * KKc + tid * 4;
  #pragma unroll
  for (int k = 0; k < Kc; ++k) {
    float4 c = *(const float4*)&chebT[((size_t)k * Nc + m) * Nc + tid * 4];
    ushort4 o;
    o.x = f2bf(c.x * e0); o.y = f2bf(c.y * e1);
    o.z = f2bf(c.z * e2); o.w = f2bf(c.w * e3);
    *(ushort4*)(ap + k * Nc) = o;
  }
}

// ---------------------------------------------------------------------------
// MFMA GEMM: C[m][n] = sum_k A[m][k]*B[n][k].
// MODE 0: bf16 C. MODE 1: fp32 relu C. MODE 2: bf16 sigmoid(C + bias[m][n]).
// ---------------------------------------------------------------------------
template <int MODE>
__global__ __launch_bounds__(256) void mfma_gemm_bt(
    const unsigned short* __restrict__ A, const unsigned short* __restrict__ B,
    void* __restrict__ Cv, const float* __restrict__ bias, int K, int CN,
    long long Abatch, long long Bbatch, long long Cbatch) {
  __shared__ unsigned short As[128 * 64];
  __shared__ unsigned short Bs[128 * 64];
  int b = blockIdx.z;
  int tid = threadIdx.x, wave = tid >> 6, lane = tid & 63;
  const unsigned short* Ag = A + (size_t)b * Abatch + (size_t)blockIdx.y * 128 * K;
  const unsigned short* Bg = B + (size_t)b * Bbatch + (size_t)blockIdx.x * 128 * K;
  f32x4 zero = {0.f, 0.f, 0.f, 0.f};
  f32x4 acc[4][4];
  #pragma unroll
  for (int i = 0; i < 4; ++i)
    #pragma unroll
    for (int j = 0; j < 4; ++j) acc[i][j] = zero;
  gemm_core(Ag, Bg, K, K, K, As, Bs, wave, lane, acc);
  int rw = (wave >> 1) * 64, cw = (wave & 1) * 64;
  int q = lane >> 4, cl = lane & 15;
  #pragma unroll
  for (int i = 0; i < 4; ++i)
    #pragma unroll
    for (int e = 0; e < 4; ++e) {
      size_t P = (size_t)blockIdx.y * 128 + rw + i * 16 + q * 4 + e;
      #pragma unroll
      for (int j = 0; j < 4; ++j) {
        size_t Q = (size_t)blockIdx.x * 128 + cw + j * 16 + cl;
        if (MODE == 0) {
          ((unsigned short*)Cv)[(size_t)b * Cbatch + P * CN + Q] = f2bf(acc[i][j][e]);
        } else if (MODE == 1) {
          ((float*)Cv)[(size_t)b * Cbatch + P * CN + Q] = fmaxf(acc[i][j][e], 0.f);
        } else {
          float v = acc[i][j][e] + bias[P * CN + Q];
          ((unsigned short*)Cv)[(size_t)b * Cbatch + P * CN + Q] =
              f2bf(1.f / (1.f + __expf(-v)));
        }
      }
    }
}

// ---------------------------------------------------------------------------
// y2 GEMM: for z=(bl,t): ycat[bl][(o*24+t)][k*1024+n] =
//   sum_f tcat[(k*64+o)][f] * xt2[bbase+bl][n][t][f].  K=64.
// ---------------------------------------------------------------------------
__global__ __launch_bounds__(256) void y2_gemm(
    const unsigned short* __restrict__ tcat, const unsigned short* __restrict__ xt2,
    unsigned short* __restrict__ ycat, int bbase) {
  __shared__ unsigned short As[128 * 64];
  __shared__ unsigned short Bs[128 * 64];
  int z = blockIdx.z;
  int bl = z / 24, t = z - bl * 24;
  int tid = threadIdx.x, wave = tid >> 6, lane = tid & 63;
  const unsigned short* Ag = tcat + (size_t)blockIdx.y * 128 * 64;
  const unsigned short* Bg = xt2 + ((size_t)(bbase + bl) * Nc + (size_t)blockIdx.x * 128) * Cc
                             + (size_t)t * 64;
  f32x4 zero = {0.f, 0.f, 0.f, 0.f};
  f32x4 acc[4][4];
  #pragma unroll
  for (int i = 0; i < 4; ++i)
    #pragma unroll
    for (int j = 0; j < 4; ++j) acc[i][j] = zero;
  gemm_core(Ag, Bg, 64, Cc, 64, As, Bs, wave, lane, acc);
  int rw = (wave >> 1) * 64, cw = (wave & 1) * 64;
  int q = lane >> 4, cl = lane & 15;
  unsigned short* yb = ycat + (size_t)bl * Cc * KKc + (size_t)t * KKc;
  #pragma unroll
  for (int i = 0; i < 4; ++i)
    #pragma unroll
    for (int e = 0; e < 4; ++e) {
      int m2 = blockIdx.y * 128 + rw + i * 16 + q * 4 + e;
      if (m2 < 192) {
        int kk = m2 >> 6, o = m2 & 63;
        unsigned short* dst = yb + (size_t)o * 24 * KKc + kk * Nc;
        #pragma unroll
        for (int j = 0; j < 4; ++j)
          dst[blockIdx.x * 128 + cw + j * 16 + cl] = f2bf(acc[i][j][e]);
      }
    }
}

// ---------------------------------------------------------------------------
extern "C" void kernel_launch(void* const* d_in, const int* in_sizes, int n_in,
                              void* d_out, int out_size, void* d_ws, size_t ws_size,
                              hipStream_t stream) {
  const float* x     = (const float*)d_in[0];
  const float* W1    = (const float*)d_in[1];
  const float* W2    = (const float*)d_in[2];
  const float* W3    = (const float*)d_in[3];
  const float* bs    = (const float*)d_in[4];
  const float* Vs    = (const float*)d_in[5];
  const float* cheb  = (const float*)d_in[6];
  const float* Theta = (const float*)d_in[7];
  float* out = (float*)d_out;

  // ws_size-adaptive: 1 pass of 16 batches (needs 348.2 MB) or 2 passes of 8
  // (needs 222.3 MB, the R4-verified layout). Deterministic per harness.
  int passes, blcount;
  if (ws_size >= 348160000ULL) { passes = 1; blcount = 16; }
  else                         { passes = 2; blcount = 8;  }

  char* w = (char*)d_ws;
  size_t Y  = (size_t)blcount * Cc * KKc * 2;   // ycat bytes
  size_t A2 = (size_t)blcount * Nc * KKc * 2;   // Acat bytes
  unsigned short* ycat = (unsigned short*)w;
  unsigned short* Acat = (unsigned short*)(w + Y);
  unsigned short* ST   = (unsigned short*)(w + Y + A2);                 // 33.55 MB
  float* chebT         = (float*)(w + Y + A2 + 33554432);               // 12.58 MB
  unsigned short* xt2  = (unsigned short*)(w + Y + A2 + 46137344);      // 50.33 MB
  unsigned short* tcat = (unsigned short*)(w + Y + A2 + 96468992);      // 32 KB
  // Front-phase temps aliased into ycat (all dead before y2 writes ycat):
  unsigned short* lhsb = (unsigned short*)w;                // 2 MB
  unsigned short* rhsb = (unsigned short*)(w + 2097152);    // 2 MB
  unsigned short* sigT = (unsigned short*)(w + 4194304);    // 33.55 MB
  float* bsT           = (float*)(w + 37748736);            // 4.19 MB
  unsigned short* Vsbf = (unsigned short*)(w + 41943040);   // 2 MB (ends 44.04 MB <= 75.5)

  xprep_kernel<<<Bc * Nc / 4, 256, 0, stream>>>(x, W1, W2, W3, xt2, lhsb, rhsb);
  misc_kernel<<<1344, 256, 0, stream>>>(Vs, Theta, bs, Vsbf, tcat, bsT);
  // sigT[p][q] = sigmoid(sum_t rhsb[p,t]*lhsb[q,t] + bsT[p][q])
  mfma_gemm_bt<2><<<dim3(8, 8, 16), 256, 0, stream>>>(
      rhsb, lhsb, sigT, bsT, 64, Nc,
      (long long)Nc * 64, (long long)Nc * 64, (long long)Nc * Nc);
  // ST[b][j][i] = sum_kk sigT[b][j][kk] * Vs[i][kk]
  mfma_gemm_bt<0><<<dim3(8, 8, 16), 256, 0, stream>>>(
      sigT, Vsbf, ST, nullptr, Nc, Nc,
      (long long)Nc * Nc, 0LL, (long long)Nc * Nc);
  chebT_kernel<<<dim3(16, 16, 3), 256, 0, stream>>>(cheb, chebT);

  for (int pass = 0; pass < passes; ++pass) {
    int bbase = pass * blcount;
    masksoft_kernel<<<blcount * Nc, 256, 0, stream>>>(chebT, ST, Acat, bbase);
    y2_gemm<<<dim3(Nc / 128, 2, blcount * 24), 256, 0, stream>>>(tcat, xt2, ycat, bbase);
    // out[b][m][o*24+t] = relu( sum_{kk<3072} Acat[bl][m][kk] * ycat[bl][c''][kk] )
    mfma_gemm_bt<1><<<dim3(Cc / 128, Nc / 128, blcount), 256, 0, stream>>>(
        Acat, ycat, out + (size_t)bbase * Nc * Cc, nullptr, KKc, Cc,
        (long long)Nc * KKc, (long long)Cc * KKc, (long long)Nc * Cc);
  }
}